// Round 6
// baseline (633.092 us; speedup 1.0000x reference)
//
#include <hip/hip_runtime.h>

#define N_NODES 100000
#define N_EDGES 3200000
#define FEAT 64
#define NUM_RELS 16
#define N_RANGES 8
#define CAP 64
#define OVF_CAP 65536

typedef float f32x4 __attribute__((ext_vector_type(4)));
typedef float f32x16 __attribute__((ext_vector_type(16)));
typedef short s16x8 __attribute__((ext_vector_type(8)));
typedef int   i32x2 __attribute__((ext_vector_type(2)));
typedef int   i32x4 __attribute__((ext_vector_type(4)));

__device__ __forceinline__ unsigned short f32_to_bf16_rne(float x) {
    unsigned int u = __float_as_uint(x);
    unsigned int r = (u + 0x7fffu + ((u >> 16) & 1u)) >> 16;
    return (unsigned short)r;
}
__device__ __forceinline__ float bf16_to_f32(unsigned short s) {
    return __uint_as_float(((unsigned int)s) << 16);
}

// ---------------- conversion kernels ----------------
__global__ __launch_bounds__(256) void cvt_h_kernel(const float4* __restrict__ h4,
                                                    ushort4* __restrict__ hb4, int n4)
{
    int i = blockIdx.x * 256 + threadIdx.x;
    if (i < n4) {
        float4 v = h4[i];
        ushort4 o;
        o.x = f32_to_bf16_rne(v.x); o.y = f32_to_bf16_rne(v.y);
        o.z = f32_to_bf16_rne(v.z); o.w = f32_to_bf16_rne(v.w);
        hb4[i] = o;
    }
}

// Wt[r][o][k] = bf16(W[r][k][o])
__global__ __launch_bounds__(256) void cvt_w_kernel(const float* __restrict__ W,
                                                    unsigned short* __restrict__ Wt)
{
    int t = blockIdx.x * 256 + threadIdx.x;          // 16*64*64 threads
    int r = t >> 12, o = (t >> 6) & 63, k = t & 63;
    Wt[t] = f32_to_bf16_rne(W[(r << 12) + (k << 6) + o]);
}

// ---------------- phase 1: dense transform T[n][r][o] = (h[n] @ W[r])  (bf16) ----
// Operand-swapped MFMA: D = mfma(W_frag, h_frag) -> D[o][n]; lane (q=lane&15)
// owns node row0+q, feats t*16 + g4*4 + {0..3} -> packed 8-B stores tiling
// full 32-B sectors (fixes the 1.5x WRITE_SIZE inflation of scalar u16 stores).
__global__ __launch_bounds__(256) void gemm_T_kernel(
    const unsigned short* __restrict__ hb,   // [N][64] bf16
    const unsigned short* __restrict__ Wt,   // [16][o][k] bf16
    unsigned short* __restrict__ T)          // [N][16][64] bf16
{
    const int lane  = threadIdx.x & 63;
    const int w     = threadIdx.x >> 6;
    const int row0  = blockIdx.x * 64 + w * 16;      // this wave's 16 nodes
    const int q     = lane & 15;
    const int g4    = lane >> 4;

    const int rowA = min(row0 + q, N_NODES - 1);
    const unsigned short* ap = hb + ((size_t)rowA << 6) + (g4 << 3);
    const s16x8 a0 = *reinterpret_cast<const s16x8*>(ap);
    const s16x8 a1 = *reinterpret_cast<const s16x8*>(ap + 32);

    const unsigned short* wbase = Wt + ((size_t)q << 6) + (g4 << 3);
    const bool doStore = (row0 + q) < N_NODES;
    unsigned short* tpn = T + ((size_t)(row0 + q) << 10) + (g4 << 2);

    auto loadB = [&](s16x8* Bf, int r) {
        const unsigned short* wp = wbase + ((size_t)r << 12);
        #pragma unroll
        for (int t = 0; t < 4; ++t)
            #pragma unroll
            for (int kh = 0; kh < 2; ++kh)
                Bf[t * 2 + kh] = *reinterpret_cast<const s16x8*>(wp + (t << 10) + (kh << 5));
    };
    auto compStore = [&](const s16x8* Bf, int rr) {
        f32x4 acc[4] = {f32x4{0,0,0,0}, f32x4{0,0,0,0}, f32x4{0,0,0,0}, f32x4{0,0,0,0}};
        #pragma unroll
        for (int t = 0; t < 4; ++t) {
            acc[t] = __builtin_amdgcn_mfma_f32_16x16x32_bf16(Bf[t*2+0], a0, acc[t], 0, 0, 0);
            acc[t] = __builtin_amdgcn_mfma_f32_16x16x32_bf16(Bf[t*2+1], a1, acc[t], 0, 0, 0);
        }
        if (doStore) {
            unsigned short* tp = tpn + (rr << 6);
            #pragma unroll
            for (int t = 0; t < 4; ++t) {
                i32x2 pk;
                pk.x = (int)((unsigned)f32_to_bf16_rne(acc[t][0]) |
                             ((unsigned)f32_to_bf16_rne(acc[t][1]) << 16));
                pk.y = (int)((unsigned)f32_to_bf16_rne(acc[t][2]) |
                             ((unsigned)f32_to_bf16_rne(acc[t][3]) << 16));
                __builtin_nontemporal_store(pk, reinterpret_cast<i32x2*>(tp + (t << 4)));
            }
        }
    };

    s16x8 B0[8], B1[8];
    loadB(B0, 0);
    #pragma unroll
    for (int rp = 0; rp < 16; rp += 2) {
        loadB(B1, rp + 1);
        compStore(B0, rp);
        if (rp + 2 < 16) loadB(B0, rp + 2);
        compStore(B1, rp + 1);
    }
}

// ---------------- phase 2 (bucket path): range-split bucketed scatter ----------
__global__ __launch_bounds__(256) void fill_bucket_kernel(
    const int* __restrict__ src, const int* __restrict__ dst,
    const int* __restrict__ rel, const float* __restrict__ norm,
    int* __restrict__ cnt, i32x2* __restrict__ pay,
    int* __restrict__ ovfc, i32x4* __restrict__ ovf, int lo, int hi)
{
    int e = blockIdx.x * 256 + threadIdx.x;
    if (e < N_EDGES) {
        int d = __builtin_nontemporal_load(&dst[e]);
        if (d >= lo && d < hi) {
            int s   = __builtin_nontemporal_load(&src[e]);
            int rl  = __builtin_nontemporal_load(&rel[e]);
            float nv = __builtin_nontemporal_load(&norm[e]);
            int pos = atomicAdd(&cnt[d], 1);
            if (pos < CAP) {
                i32x2 p; p.x = (s << 4) | rl; p.y = __float_as_int(nv);
                pay[(size_t)d * CAP + pos] = p;
            } else {
                int op = atomicAdd(ovfc, 1);
                if (op < OVF_CAP) {
                    i32x4 o; o.x = d; o.y = (s << 4) | rl;
                    o.z = __float_as_int(nv); o.w = 0;
                    ovf[op] = o;
                }
            }
        }
    }
}

// ---------------- phase 3 (bucket path): per-dst gather/sum + relu -------------
__global__ __launch_bounds__(256) void aggregate_bucket_kernel(
    const unsigned short* __restrict__ T,    // [N][16][64] bf16
    const i32x2* __restrict__ pay,           // [N][CAP] {src*16+rel, norm}
    const int* __restrict__ cnt,             // [N]
    const int* __restrict__ ovfc, const i32x4* __restrict__ ovf,
    float* __restrict__ out)                 // [N][64]
{
    const int lane = threadIdx.x & 63;
    const int d    = blockIdx.x * 4 + (threadIdx.x >> 6);   // grid covers N exactly

    const int degRaw = __builtin_amdgcn_readfirstlane(cnt[d]);
    const int deg    = min(degRaw, CAP);
    const i32x2* pp  = pay + (size_t)d * CAP;

    float acc = 0.f;
    int i = 0;
    for (; i + 4 <= deg; i += 4) {
        i32x2 p0 = __builtin_nontemporal_load(&pp[i]);
        i32x2 p1 = __builtin_nontemporal_load(&pp[i + 1]);
        i32x2 p2 = __builtin_nontemporal_load(&pp[i + 2]);
        i32x2 p3 = __builtin_nontemporal_load(&pp[i + 3]);
        const unsigned short t0 = T[((size_t)(p0.x >> 4) << 10) + ((p0.x & 15) << 6) + lane];
        const unsigned short t1 = T[((size_t)(p1.x >> 4) << 10) + ((p1.x & 15) << 6) + lane];
        const unsigned short t2 = T[((size_t)(p2.x >> 4) << 10) + ((p2.x & 15) << 6) + lane];
        const unsigned short t3 = T[((size_t)(p3.x >> 4) << 10) + ((p3.x & 15) << 6) + lane];
        acc = fmaf(__int_as_float(p0.y), bf16_to_f32(t0), acc);
        acc = fmaf(__int_as_float(p1.y), bf16_to_f32(t1), acc);
        acc = fmaf(__int_as_float(p2.y), bf16_to_f32(t2), acc);
        acc = fmaf(__int_as_float(p3.y), bf16_to_f32(t3), acc);
    }
    for (; i < deg; ++i) {
        i32x2 p = __builtin_nontemporal_load(&pp[i]);
        const unsigned short t = T[((size_t)(p.x >> 4) << 10) + ((p.x & 15) << 6) + lane];
        acc = fmaf(__int_as_float(p.y), bf16_to_f32(t), acc);
    }
    if (degRaw > CAP) {                       // exact overflow handling (rare)
        const int no = min(__builtin_amdgcn_readfirstlane(*ovfc), OVF_CAP);
        for (int j = 0; j < no; ++j) {
            i32x4 o = ovf[j];
            if (o.x == d) {
                const unsigned short t =
                    T[((size_t)(o.y >> 4) << 10) + ((o.y & 15) << 6) + lane];
                acc = fmaf(__int_as_float(o.z), bf16_to_f32(t), acc);
            }
        }
    }
    out[((size_t)d << 6) + lane] = fmaxf(acc, 0.f);
}

// ================= CSR path (round-5, used if ws too small for buckets) =======
__global__ __launch_bounds__(256) void hist_kernel(const int* __restrict__ dst,
                                                   int* __restrict__ cnt)
{
    int e = blockIdx.x * 256 + threadIdx.x;
    if (e < N_EDGES) atomicAdd(&cnt[__builtin_nontemporal_load(&dst[e])], 1);
}

__global__ __launch_bounds__(1024) void scan1_kernel(const int* __restrict__ cnt,
                                                     int* __restrict__ ofs,
                                                     int* __restrict__ btot, int n)
{
    __shared__ int tmp[1024];
    const int tid = threadIdx.x;
    const int i = blockIdx.x * 1024 + tid;
    int v = (i < n) ? cnt[i] : 0;
    tmp[tid] = v; __syncthreads();
    #pragma unroll
    for (int off = 1; off < 1024; off <<= 1) {
        int t = (tid >= off) ? tmp[tid - off] : 0;
        __syncthreads();
        tmp[tid] += t;
        __syncthreads();
    }
    if (i < n) ofs[i] = tmp[tid] - v;
    if (tid == 1023) btot[blockIdx.x] = tmp[tid];
}

__global__ __launch_bounds__(128) void scan2_kernel(int* __restrict__ btot,
                                                    int* __restrict__ bbase, int nb)
{
    __shared__ int tmp[128];
    const int tid = threadIdx.x;
    int v = (tid < nb) ? btot[tid] : 0;
    tmp[tid] = v; __syncthreads();
    #pragma unroll
    for (int off = 1; off < 128; off <<= 1) {
        int t = (tid >= off) ? tmp[tid - off] : 0;
        __syncthreads();
        tmp[tid] += t;
        __syncthreads();
    }
    if (tid < nb) bbase[tid] = tmp[tid] - v;
}

__global__ __launch_bounds__(1024) void scan3_kernel(int* __restrict__ ofs,
                                                     int* __restrict__ cur,
                                                     const int* __restrict__ bbase, int n)
{
    const int i = blockIdx.x * 1024 + threadIdx.x;
    if (i < n) {
        int o = ofs[i] + bbase[blockIdx.x];
        ofs[i] = o;
        cur[i] = o;
    }
    if (i == 0) ofs[n] = N_EDGES;
}

__global__ __launch_bounds__(256) void fill_kernel(const int* __restrict__ src,
                                                   const int* __restrict__ dst,
                                                   const int* __restrict__ rel,
                                                   const float* __restrict__ norm,
                                                   int* __restrict__ cur,
                                                   i32x2* __restrict__ pay,
                                                   int lo, int hi)
{
    int e = blockIdx.x * 256 + threadIdx.x;
    if (e < N_EDGES) {
        int d = __builtin_nontemporal_load(&dst[e]);
        if (d >= lo && d < hi) {
            int s  = __builtin_nontemporal_load(&src[e]);
            int rl = __builtin_nontemporal_load(&rel[e]);
            float nv = __builtin_nontemporal_load(&norm[e]);
            int pos = atomicAdd(&cur[d], 1);
            i32x2 p; p.x = (s << 4) | rl; p.y = __float_as_int(nv);
            pay[pos] = p;
        }
    }
}

__global__ __launch_bounds__(256) void aggregate_kernel(
    const unsigned short* __restrict__ T,
    const i32x2* __restrict__ pay,
    const int* __restrict__ ofs,
    float* __restrict__ out)
{
    const int lane = threadIdx.x & 63;
    const int d    = blockIdx.x * 4 + (threadIdx.x >> 6);

    const int beg = __builtin_amdgcn_readfirstlane(ofs[d]);
    const int end = __builtin_amdgcn_readfirstlane(ofs[d + 1]);

    float acc = 0.f;
    int i = beg;
    for (; i + 4 <= end; i += 4) {
        i32x2 p0 = __builtin_nontemporal_load(&pay[i]);
        i32x2 p1 = __builtin_nontemporal_load(&pay[i + 1]);
        i32x2 p2 = __builtin_nontemporal_load(&pay[i + 2]);
        i32x2 p3 = __builtin_nontemporal_load(&pay[i + 3]);
        const unsigned short t0 = T[((size_t)(p0.x >> 4) << 10) + ((p0.x & 15) << 6) + lane];
        const unsigned short t1 = T[((size_t)(p1.x >> 4) << 10) + ((p1.x & 15) << 6) + lane];
        const unsigned short t2 = T[((size_t)(p2.x >> 4) << 10) + ((p2.x & 15) << 6) + lane];
        const unsigned short t3 = T[((size_t)(p3.x >> 4) << 10) + ((p3.x & 15) << 6) + lane];
        acc = fmaf(__int_as_float(p0.y), bf16_to_f32(t0), acc);
        acc = fmaf(__int_as_float(p1.y), bf16_to_f32(t1), acc);
        acc = fmaf(__int_as_float(p2.y), bf16_to_f32(t2), acc);
        acc = fmaf(__int_as_float(p3.y), bf16_to_f32(t3), acc);
    }
    for (; i < end; ++i) {
        i32x2 p = __builtin_nontemporal_load(&pay[i]);
        const unsigned short t = T[((size_t)(p.x >> 4) << 10) + ((p.x & 15) << 6) + lane];
        acc = fmaf(__int_as_float(p.y), bf16_to_f32(t), acc);
    }
    out[((size_t)d << 6) + lane] = fmaxf(acc, 0.f);
}

// ---------------- atomic fallback (no workspace) ----------------
__global__ __launch_bounds__(256) void rgcn_edge_kernel(
    const float* __restrict__ h, const float* __restrict__ W,
    const float* __restrict__ norm, const int* __restrict__ src,
    const int* __restrict__ dst, const int* __restrict__ rel,
    float* __restrict__ out)
{
    const int lane = threadIdx.x & 63;
    const int w    = threadIdx.x >> 6;
    const int r    = blockIdx.x & 15;
    const int inst = blockIdx.x >> 4;
    const int wavesPerRel = (gridDim.x >> 4) * 4;
    const int wi   = inst * 4 + w;

    float wreg[64];
    const float* Wr = W + (size_t)r * (FEAT * FEAT) + lane;
    #pragma unroll
    for (int d = 0; d < 64; ++d) wreg[d] = Wr[d * 64];

    const int nChunks = N_EDGES / 64;
    for (int c = wi; c < nChunks; c += wavesPerRel) {
        const int base = c * 64;
        unsigned long long m = __ballot(rel[base + lane] == r);
        while (m) {
            const int idx = __ffsll(m) - 1;
            m &= (m - 1);
            const int e = base + idx;
            const int se = __builtin_amdgcn_readfirstlane(src[e]);
            const int de = __builtin_amdgcn_readfirstlane(dst[e]);
            const float nv = __uint_as_float(
                __builtin_amdgcn_readfirstlane(__float_as_uint(norm[e])));
            const float* hp = h + ((size_t)se << 6);
            f32x16 ha, hb2, hc, hd;
            asm volatile(
                "s_load_dwordx16 %0, %4, 0x0\n\ts_load_dwordx16 %1, %4, 0x40\n\t"
                "s_load_dwordx16 %2, %4, 0x80\n\ts_load_dwordx16 %3, %4, 0xc0\n\t"
                "s_waitcnt lgkmcnt(0)"
                : "=&s"(ha), "=&s"(hb2), "=&s"(hc), "=&s"(hd) : "s"(hp));
            float a0 = 0.f, a1 = 0.f, a2 = 0.f, a3 = 0.f;
            #pragma unroll
            for (int j = 0; j < 16; ++j) {
                a0 = fmaf(ha[j], wreg[j], a0);       a1 = fmaf(hb2[j], wreg[16 + j], a1);
                a2 = fmaf(hc[j], wreg[32 + j], a2);  a3 = fmaf(hd[j], wreg[48 + j], a3);
            }
            unsafeAtomicAdd(&out[(size_t)de * FEAT + lane], ((a0 + a1) + (a2 + a3)) * nv);
        }
    }
}

__global__ __launch_bounds__(256) void relu_kernel(float4* __restrict__ out, int n4)
{
    int i = blockIdx.x * 256 + threadIdx.x;
    if (i < n4) {
        float4 v = out[i];
        v.x = fmaxf(v.x, 0.f); v.y = fmaxf(v.y, 0.f);
        v.z = fmaxf(v.z, 0.f); v.w = fmaxf(v.w, 0.f);
        out[i] = v;
    }
}

// ---------------- host ----------------
static inline size_t align256(size_t x) { return (x + 255) & ~(size_t)255; }

extern "C" void kernel_launch(void* const* d_in, const int* in_sizes, int n_in,
                              void* d_out, int out_size, void* d_ws, size_t ws_size,
                              hipStream_t stream)
{
    (void)in_sizes; (void)n_in;

    const float* h    = (const float*)d_in[0];
    const float* W    = (const float*)d_in[1];
    const float* norm = (const float*)d_in[2];
    const int*   src  = (const int*)d_in[3];
    const int*   dst  = (const int*)d_in[4];
    const int*   rel  = (const int*)d_in[5];
    float*       out  = (float*)d_out;

    const size_t szT    = (size_t)N_NODES * NUM_RELS * FEAT * 2;   // 204.8 MB
    const size_t szHb   = (size_t)N_NODES * FEAT * 2;              // 12.8 MB
    const size_t szWt   = (size_t)NUM_RELS * FEAT * FEAT * 2;      // 128 KB
    const size_t szCnt  = (size_t)N_NODES * 4;
    const size_t szPayB = (size_t)N_NODES * CAP * 8;               // 51.2 MB
    const size_t szOvf  = (size_t)OVF_CAP * 16;                    // 1 MB
    const size_t szPayC = (size_t)N_EDGES * 8;                     // 25.6 MB (CSR)
    const size_t szOfs  = (size_t)(N_NODES + 1) * 4;

    const size_t needBucket = align256(szT) + align256(szHb) + align256(szWt)
                            + align256(szPayB) + align256(szCnt) + align256(256)
                            + align256(szOvf);
    const size_t needCsr    = align256(szT) + align256(szHb) + align256(szWt)
                            + align256(szPayC) + 3 * align256(szCnt)
                            + align256(szOfs) + 2 * align256(1024);

    const int n4h = N_NODES * FEAT / 4;
    const int nodesPerRange = (N_NODES + N_RANGES - 1) / N_RANGES;

    if (ws_size >= needBucket) {
        char* ws = (char*)d_ws; size_t off = 0;
        unsigned short* T    = (unsigned short*)(ws + off); off += align256(szT);
        unsigned short* hb   = (unsigned short*)(ws + off); off += align256(szHb);
        unsigned short* Wt   = (unsigned short*)(ws + off); off += align256(szWt);
        i32x2*          pay  = (i32x2*)         (ws + off); off += align256(szPayB);
        int*            cnt  = (int*)           (ws + off); off += align256(szCnt);
        int*            ovfc = (int*)           (ws + off); off += align256(256);
        i32x4*          ovf  = (i32x4*)         (ws + off); off += align256(szOvf);

        hipLaunchKernelGGL(cvt_h_kernel, dim3((n4h + 255) / 256), dim3(256), 0, stream,
                           (const float4*)h, (ushort4*)hb, n4h);
        hipLaunchKernelGGL(cvt_w_kernel, dim3(NUM_RELS * FEAT * FEAT / 256), dim3(256),
                           0, stream, W, Wt);
        hipMemsetAsync(cnt, 0, szCnt, stream);
        hipMemsetAsync(ovfc, 0, 256, stream);

        hipLaunchKernelGGL(gemm_T_kernel, dim3((N_NODES + 63) / 64), dim3(256), 0, stream,
                           hb, Wt, T);

        for (int rg = 0; rg < N_RANGES; ++rg) {
            const int lo = rg * nodesPerRange;
            const int hi = min(lo + nodesPerRange, N_NODES);
            hipLaunchKernelGGL(fill_bucket_kernel, dim3((N_EDGES + 255) / 256), dim3(256),
                               0, stream, src, dst, rel, norm, cnt, pay, ovfc, ovf, lo, hi);
        }

        hipLaunchKernelGGL(aggregate_bucket_kernel, dim3(N_NODES / 4), dim3(256), 0, stream,
                           T, pay, cnt, ovfc, ovf, out);
        return;
    }

    if (ws_size >= needCsr) {
        char* ws = (char*)d_ws; size_t off = 0;
        unsigned short* T   = (unsigned short*)(ws + off); off += align256(szT);
        unsigned short* hb  = (unsigned short*)(ws + off); off += align256(szHb);
        unsigned short* Wt  = (unsigned short*)(ws + off); off += align256(szWt);
        i32x2*          pay = (i32x2*)         (ws + off); off += align256(szPayC);
        int*            cnt = (int*)           (ws + off); off += align256(szCnt);
        int*            ofs = (int*)           (ws + off); off += align256(szOfs);
        int*            cur = (int*)           (ws + off); off += align256(szCnt);
        int*            btot= (int*)           (ws + off); off += align256(1024);
        int*            bbas= (int*)           (ws + off); off += align256(1024);

        hipLaunchKernelGGL(cvt_h_kernel, dim3((n4h + 255) / 256), dim3(256), 0, stream,
                           (const float4*)h, (ushort4*)hb, n4h);
        hipLaunchKernelGGL(cvt_w_kernel, dim3(NUM_RELS * FEAT * FEAT / 256), dim3(256),
                           0, stream, W, Wt);
        hipMemsetAsync(cnt, 0, szCnt, stream);
        hipLaunchKernelGGL(gemm_T_kernel, dim3((N_NODES + 63) / 64), dim3(256), 0, stream,
                           hb, Wt, T);
        hipLaunchKernelGGL(hist_kernel, dim3((N_EDGES + 255) / 256), dim3(256), 0, stream,
                           dst, cnt);
        const int nBlocksScan = (N_NODES + 1023) / 1024;
        hipLaunchKernelGGL(scan1_kernel, dim3(nBlocksScan), dim3(1024), 0, stream,
                           cnt, ofs, btot, N_NODES);
        hipLaunchKernelGGL(scan2_kernel, dim3(1), dim3(128), 0, stream,
                           btot, bbas, nBlocksScan);
        hipLaunchKernelGGL(scan3_kernel, dim3(nBlocksScan), dim3(1024), 0, stream,
                           ofs, cur, bbas, N_NODES);
        for (int rg = 0; rg < N_RANGES; ++rg) {
            const int lo = rg * nodesPerRange;
            const int hi = min(lo + nodesPerRange, N_NODES);
            hipLaunchKernelGGL(fill_kernel, dim3((N_EDGES + 255) / 256), dim3(256), 0, stream,
                               src, dst, rel, norm, cur, pay, lo, hi);
        }
        hipLaunchKernelGGL(aggregate_kernel, dim3(N_NODES / 4), dim3(256), 0, stream,
                           T, pay, ofs, out);
        return;
    }

    // last-resort atomic path
    hipMemsetAsync(d_out, 0, (size_t)out_size * sizeof(float), stream);
    hipLaunchKernelGGL(rgcn_edge_kernel, dim3(16 * 128), dim3(256), 0, stream,
                       h, W, norm, src, dst, rel, out);
    const int n4 = out_size / 4;
    hipLaunchKernelGGL(relu_kernel, dim3((n4 + 255) / 256), dim3(256), 0, stream,
                       (float4*)d_out, n4);
}

// Round 7
// 585.049 us; speedup vs baseline: 1.0821x; 1.0821x over previous
//
#include <hip/hip_runtime.h>

#define N_NODES 100000
#define N_EDGES 3200000
#define FEAT 64
#define NUM_RELS 16
#define N_RANGES 8
#define CAP 64
#define OVF_CAP 65536

typedef float f32x4 __attribute__((ext_vector_type(4)));
typedef float f32x16 __attribute__((ext_vector_type(16)));
typedef short s16x8 __attribute__((ext_vector_type(8)));
typedef int   i32x2 __attribute__((ext_vector_type(2)));
typedef int   i32x4 __attribute__((ext_vector_type(4)));

__device__ __forceinline__ unsigned short f32_to_bf16_rne(float x) {
    unsigned int u = __float_as_uint(x);
    unsigned int r = (u + 0x7fffu + ((u >> 16) & 1u)) >> 16;
    return (unsigned short)r;
}
__device__ __forceinline__ float bf16_to_f32(unsigned short s) {
    return __uint_as_float(((unsigned int)s) << 16);
}

// ---------------- conversion kernels ----------------
__global__ __launch_bounds__(256) void cvt_h_kernel(const float4* __restrict__ h4,
                                                    ushort4* __restrict__ hb4, int n4)
{
    int i = blockIdx.x * 256 + threadIdx.x;
    if (i < n4) {
        float4 v = h4[i];
        ushort4 o;
        o.x = f32_to_bf16_rne(v.x); o.y = f32_to_bf16_rne(v.y);
        o.z = f32_to_bf16_rne(v.z); o.w = f32_to_bf16_rne(v.w);
        hb4[i] = o;
    }
}

// Wt[r][o][k] = bf16(W[r][k][o])
__global__ __launch_bounds__(256) void cvt_w_kernel(const float* __restrict__ W,
                                                    unsigned short* __restrict__ Wt)
{
    int t = blockIdx.x * 256 + threadIdx.x;          // 16*64*64 threads
    int r = t >> 12, o = (t >> 6) & 63, k = t & 63;
    Wt[t] = f32_to_bf16_rne(W[(r << 12) + (k << 6) + o]);
}

// ---------------- phase 1: dense transform T[n][r][o] = (h[n] @ W[r])  (bf16) ----
// Operand-swapped MFMA: D = mfma(W_frag, h_frag) -> D[o][n]; lane (q=lane&15)
// owns node row0+q, feats t*16 + g4*4 + {0..3} -> packed 8-B stores.
// PLAIN stores (no nt): the 4 t-stores complete each 128-B line within a few
// cycles; write-back L2 merges and evicts once (nt flushed half-dirty 64-B
// sectors -> 2x WRITE_SIZE in round 6).
__global__ __launch_bounds__(256) void gemm_T_kernel(
    const unsigned short* __restrict__ hb,   // [N][64] bf16
    const unsigned short* __restrict__ Wt,   // [16][o][k] bf16
    unsigned short* __restrict__ T)          // [N][16][64] bf16
{
    const int lane  = threadIdx.x & 63;
    const int w     = threadIdx.x >> 6;
    const int row0  = blockIdx.x * 64 + w * 16;      // this wave's 16 nodes
    const int q     = lane & 15;
    const int g4    = lane >> 4;

    const int rowA = min(row0 + q, N_NODES - 1);
    const unsigned short* ap = hb + ((size_t)rowA << 6) + (g4 << 3);
    const s16x8 a0 = *reinterpret_cast<const s16x8*>(ap);
    const s16x8 a1 = *reinterpret_cast<const s16x8*>(ap + 32);

    const unsigned short* wbase = Wt + ((size_t)q << 6) + (g4 << 3);
    const bool doStore = (row0 + q) < N_NODES;
    unsigned short* tpn = T + ((size_t)(row0 + q) << 10) + (g4 << 2);

    auto loadB = [&](s16x8* Bf, int r) {
        const unsigned short* wp = wbase + ((size_t)r << 12);
        #pragma unroll
        for (int t = 0; t < 4; ++t)
            #pragma unroll
            for (int kh = 0; kh < 2; ++kh)
                Bf[t * 2 + kh] = *reinterpret_cast<const s16x8*>(wp + (t << 10) + (kh << 5));
    };
    auto compStore = [&](const s16x8* Bf, int rr) {
        f32x4 acc[4] = {f32x4{0,0,0,0}, f32x4{0,0,0,0}, f32x4{0,0,0,0}, f32x4{0,0,0,0}};
        #pragma unroll
        for (int t = 0; t < 4; ++t) {
            acc[t] = __builtin_amdgcn_mfma_f32_16x16x32_bf16(Bf[t*2+0], a0, acc[t], 0, 0, 0);
            acc[t] = __builtin_amdgcn_mfma_f32_16x16x32_bf16(Bf[t*2+1], a1, acc[t], 0, 0, 0);
        }
        if (doStore) {
            unsigned short* tp = tpn + (rr << 6);
            #pragma unroll
            for (int t = 0; t < 4; ++t) {
                i32x2 pk;
                pk.x = (int)((unsigned)f32_to_bf16_rne(acc[t][0]) |
                             ((unsigned)f32_to_bf16_rne(acc[t][1]) << 16));
                pk.y = (int)((unsigned)f32_to_bf16_rne(acc[t][2]) |
                             ((unsigned)f32_to_bf16_rne(acc[t][3]) << 16));
                *reinterpret_cast<i32x2*>(tp + (t << 4)) = pk;
            }
        }
    };

    s16x8 B0[8], B1[8];
    loadB(B0, 0);
    #pragma unroll
    for (int rp = 0; rp < 16; rp += 2) {
        loadB(B1, rp + 1);
        compStore(B0, rp);
        if (rp + 2 < 16) loadB(B0, rp + 2);
        compStore(B1, rp + 1);
    }
}

// ---------------- phase 2 (bucket path): range-split bucketed scatter ----------
__global__ __launch_bounds__(256) void fill_bucket_kernel(
    const int* __restrict__ src, const int* __restrict__ dst,
    const int* __restrict__ rel, const float* __restrict__ norm,
    int* __restrict__ cnt, i32x2* __restrict__ pay,
    int* __restrict__ ovfc, i32x4* __restrict__ ovf, int lo, int hi)
{
    int e = blockIdx.x * 256 + threadIdx.x;
    if (e < N_EDGES) {
        int d = __builtin_nontemporal_load(&dst[e]);
        if (d >= lo && d < hi) {
            int s   = __builtin_nontemporal_load(&src[e]);
            int rl  = __builtin_nontemporal_load(&rel[e]);
            float nv = __builtin_nontemporal_load(&norm[e]);
            int pos = atomicAdd(&cnt[d], 1);
            if (pos < CAP) {
                i32x2 p; p.x = (s << 4) | rl; p.y = __float_as_int(nv);
                pay[(size_t)d * CAP + pos] = p;
            } else {
                int op = atomicAdd(ovfc, 1);
                if (op < OVF_CAP) {
                    i32x4 o; o.x = d; o.y = (s << 4) | rl;
                    o.z = __float_as_int(nv); o.w = 0;
                    ovf[op] = o;
                }
            }
        }
    }
}

// ---------------- phase 3 (bucket path): per-dst gather/sum + relu -------------
__global__ __launch_bounds__(256) void aggregate_bucket_kernel(
    const unsigned short* __restrict__ T,    // [N][16][64] bf16
    const i32x2* __restrict__ pay,           // [N][CAP] {src*16+rel, norm}
    const int* __restrict__ cnt,             // [N]
    const int* __restrict__ ovfc, const i32x4* __restrict__ ovf,
    float* __restrict__ out)                 // [N][64]
{
    const int lane = threadIdx.x & 63;
    const int d    = blockIdx.x * 4 + (threadIdx.x >> 6);   // grid covers N exactly

    const int degRaw = __builtin_amdgcn_readfirstlane(cnt[d]);
    const int deg    = min(degRaw, CAP);
    const i32x2* pp  = pay + (size_t)d * CAP;

    float acc = 0.f;
    int i = 0;
    for (; i + 4 <= deg; i += 4) {
        i32x2 p0 = __builtin_nontemporal_load(&pp[i]);
        i32x2 p1 = __builtin_nontemporal_load(&pp[i + 1]);
        i32x2 p2 = __builtin_nontemporal_load(&pp[i + 2]);
        i32x2 p3 = __builtin_nontemporal_load(&pp[i + 3]);
        const unsigned short t0 = T[((size_t)(p0.x >> 4) << 10) + ((p0.x & 15) << 6) + lane];
        const unsigned short t1 = T[((size_t)(p1.x >> 4) << 10) + ((p1.x & 15) << 6) + lane];
        const unsigned short t2 = T[((size_t)(p2.x >> 4) << 10) + ((p2.x & 15) << 6) + lane];
        const unsigned short t3 = T[((size_t)(p3.x >> 4) << 10) + ((p3.x & 15) << 6) + lane];
        acc = fmaf(__int_as_float(p0.y), bf16_to_f32(t0), acc);
        acc = fmaf(__int_as_float(p1.y), bf16_to_f32(t1), acc);
        acc = fmaf(__int_as_float(p2.y), bf16_to_f32(t2), acc);
        acc = fmaf(__int_as_float(p3.y), bf16_to_f32(t3), acc);
    }
    for (; i < deg; ++i) {
        i32x2 p = __builtin_nontemporal_load(&pp[i]);
        const unsigned short t = T[((size_t)(p.x >> 4) << 10) + ((p.x & 15) << 6) + lane];
        acc = fmaf(__int_as_float(p.y), bf16_to_f32(t), acc);
    }
    if (degRaw > CAP) {                       // exact overflow handling (rare)
        const int no = min(__builtin_amdgcn_readfirstlane(*ovfc), OVF_CAP);
        for (int j = 0; j < no; ++j) {
            i32x4 o = ovf[j];
            if (o.x == d) {
                const unsigned short t =
                    T[((size_t)(o.y >> 4) << 10) + ((o.y & 15) << 6) + lane];
                acc = fmaf(__int_as_float(o.z), bf16_to_f32(t), acc);
            }
        }
    }
    out[((size_t)d << 6) + lane] = fmaxf(acc, 0.f);
}

// ================= CSR path (round-5, used if ws too small for buckets) =======
__global__ __launch_bounds__(256) void hist_kernel(const int* __restrict__ dst,
                                                   int* __restrict__ cnt)
{
    int e = blockIdx.x * 256 + threadIdx.x;
    if (e < N_EDGES) atomicAdd(&cnt[__builtin_nontemporal_load(&dst[e])], 1);
}

__global__ __launch_bounds__(1024) void scan1_kernel(const int* __restrict__ cnt,
                                                     int* __restrict__ ofs,
                                                     int* __restrict__ btot, int n)
{
    __shared__ int tmp[1024];
    const int tid = threadIdx.x;
    const int i = blockIdx.x * 1024 + tid;
    int v = (i < n) ? cnt[i] : 0;
    tmp[tid] = v; __syncthreads();
    #pragma unroll
    for (int off = 1; off < 1024; off <<= 1) {
        int t = (tid >= off) ? tmp[tid - off] : 0;
        __syncthreads();
        tmp[tid] += t;
        __syncthreads();
    }
    if (i < n) ofs[i] = tmp[tid] - v;
    if (tid == 1023) btot[blockIdx.x] = tmp[tid];
}

__global__ __launch_bounds__(128) void scan2_kernel(int* __restrict__ btot,
                                                    int* __restrict__ bbase, int nb)
{
    __shared__ int tmp[128];
    const int tid = threadIdx.x;
    int v = (tid < nb) ? btot[tid] : 0;
    tmp[tid] = v; __syncthreads();
    #pragma unroll
    for (int off = 1; off < 128; off <<= 1) {
        int t = (tid >= off) ? tmp[tid - off] : 0;
        __syncthreads();
        tmp[tid] += t;
        __syncthreads();
    }
    if (tid < nb) bbase[tid] = tmp[tid] - v;
}

__global__ __launch_bounds__(1024) void scan3_kernel(int* __restrict__ ofs,
                                                     int* __restrict__ cur,
                                                     const int* __restrict__ bbase, int n)
{
    const int i = blockIdx.x * 1024 + threadIdx.x;
    if (i < n) {
        int o = ofs[i] + bbase[blockIdx.x];
        ofs[i] = o;
        cur[i] = o;
    }
    if (i == 0) ofs[n] = N_EDGES;
}

__global__ __launch_bounds__(256) void fill_kernel(const int* __restrict__ src,
                                                   const int* __restrict__ dst,
                                                   const int* __restrict__ rel,
                                                   const float* __restrict__ norm,
                                                   int* __restrict__ cur,
                                                   i32x2* __restrict__ pay,
                                                   int lo, int hi)
{
    int e = blockIdx.x * 256 + threadIdx.x;
    if (e < N_EDGES) {
        int d = __builtin_nontemporal_load(&dst[e]);
        if (d >= lo && d < hi) {
            int s  = __builtin_nontemporal_load(&src[e]);
            int rl = __builtin_nontemporal_load(&rel[e]);
            float nv = __builtin_nontemporal_load(&norm[e]);
            int pos = atomicAdd(&cur[d], 1);
            i32x2 p; p.x = (s << 4) | rl; p.y = __float_as_int(nv);
            pay[pos] = p;
        }
    }
}

__global__ __launch_bounds__(256) void aggregate_kernel(
    const unsigned short* __restrict__ T,
    const i32x2* __restrict__ pay,
    const int* __restrict__ ofs,
    float* __restrict__ out)
{
    const int lane = threadIdx.x & 63;
    const int d    = blockIdx.x * 4 + (threadIdx.x >> 6);

    const int beg = __builtin_amdgcn_readfirstlane(ofs[d]);
    const int end = __builtin_amdgcn_readfirstlane(ofs[d + 1]);

    float acc = 0.f;
    int i = beg;
    for (; i + 4 <= end; i += 4) {
        i32x2 p0 = __builtin_nontemporal_load(&pay[i]);
        i32x2 p1 = __builtin_nontemporal_load(&pay[i + 1]);
        i32x2 p2 = __builtin_nontemporal_load(&pay[i + 2]);
        i32x2 p3 = __builtin_nontemporal_load(&pay[i + 3]);
        const unsigned short t0 = T[((size_t)(p0.x >> 4) << 10) + ((p0.x & 15) << 6) + lane];
        const unsigned short t1 = T[((size_t)(p1.x >> 4) << 10) + ((p1.x & 15) << 6) + lane];
        const unsigned short t2 = T[((size_t)(p2.x >> 4) << 10) + ((p2.x & 15) << 6) + lane];
        const unsigned short t3 = T[((size_t)(p3.x >> 4) << 10) + ((p3.x & 15) << 6) + lane];
        acc = fmaf(__int_as_float(p0.y), bf16_to_f32(t0), acc);
        acc = fmaf(__int_as_float(p1.y), bf16_to_f32(t1), acc);
        acc = fmaf(__int_as_float(p2.y), bf16_to_f32(t2), acc);
        acc = fmaf(__int_as_float(p3.y), bf16_to_f32(t3), acc);
    }
    for (; i < end; ++i) {
        i32x2 p = __builtin_nontemporal_load(&pay[i]);
        const unsigned short t = T[((size_t)(p.x >> 4) << 10) + ((p.x & 15) << 6) + lane];
        acc = fmaf(__int_as_float(p.y), bf16_to_f32(t), acc);
    }
    out[((size_t)d << 6) + lane] = fmaxf(acc, 0.f);
}

// ---------------- atomic fallback (no workspace) ----------------
__global__ __launch_bounds__(256) void rgcn_edge_kernel(
    const float* __restrict__ h, const float* __restrict__ W,
    const float* __restrict__ norm, const int* __restrict__ src,
    const int* __restrict__ dst, const int* __restrict__ rel,
    float* __restrict__ out)
{
    const int lane = threadIdx.x & 63;
    const int w    = threadIdx.x >> 6;
    const int r    = blockIdx.x & 15;
    const int inst = blockIdx.x >> 4;
    const int wavesPerRel = (gridDim.x >> 4) * 4;
    const int wi   = inst * 4 + w;

    float wreg[64];
    const float* Wr = W + (size_t)r * (FEAT * FEAT) + lane;
    #pragma unroll
    for (int d = 0; d < 64; ++d) wreg[d] = Wr[d * 64];

    const int nChunks = N_EDGES / 64;
    for (int c = wi; c < nChunks; c += wavesPerRel) {
        const int base = c * 64;
        unsigned long long m = __ballot(rel[base + lane] == r);
        while (m) {
            const int idx = __ffsll(m) - 1;
            m &= (m - 1);
            const int e = base + idx;
            const int se = __builtin_amdgcn_readfirstlane(src[e]);
            const int de = __builtin_amdgcn_readfirstlane(dst[e]);
            const float nv = __uint_as_float(
                __builtin_amdgcn_readfirstlane(__float_as_uint(norm[e])));
            const float* hp = h + ((size_t)se << 6);
            f32x16 ha, hb2, hc, hd;
            asm volatile(
                "s_load_dwordx16 %0, %4, 0x0\n\ts_load_dwordx16 %1, %4, 0x40\n\t"
                "s_load_dwordx16 %2, %4, 0x80\n\ts_load_dwordx16 %3, %4, 0xc0\n\t"
                "s_waitcnt lgkmcnt(0)"
                : "=&s"(ha), "=&s"(hb2), "=&s"(hc), "=&s"(hd) : "s"(hp));
            float a0 = 0.f, a1 = 0.f, a2 = 0.f, a3 = 0.f;
            #pragma unroll
            for (int j = 0; j < 16; ++j) {
                a0 = fmaf(ha[j], wreg[j], a0);       a1 = fmaf(hb2[j], wreg[16 + j], a1);
                a2 = fmaf(hc[j], wreg[32 + j], a2);  a3 = fmaf(hd[j], wreg[48 + j], a3);
            }
            unsafeAtomicAdd(&out[(size_t)de * FEAT + lane], ((a0 + a1) + (a2 + a3)) * nv);
        }
    }
}

__global__ __launch_bounds__(256) void relu_kernel(float4* __restrict__ out, int n4)
{
    int i = blockIdx.x * 256 + threadIdx.x;
    if (i < n4) {
        float4 v = out[i];
        v.x = fmaxf(v.x, 0.f); v.y = fmaxf(v.y, 0.f);
        v.z = fmaxf(v.z, 0.f); v.w = fmaxf(v.w, 0.f);
        out[i] = v;
    }
}

// ---------------- host ----------------
static inline size_t align256(size_t x) { return (x + 255) & ~(size_t)255; }

extern "C" void kernel_launch(void* const* d_in, const int* in_sizes, int n_in,
                              void* d_out, int out_size, void* d_ws, size_t ws_size,
                              hipStream_t stream)
{
    (void)in_sizes; (void)n_in;

    const float* h    = (const float*)d_in[0];
    const float* W    = (const float*)d_in[1];
    const float* norm = (const float*)d_in[2];
    const int*   src  = (const int*)d_in[3];
    const int*   dst  = (const int*)d_in[4];
    const int*   rel  = (const int*)d_in[5];
    float*       out  = (float*)d_out;

    const size_t szT    = (size_t)N_NODES * NUM_RELS * FEAT * 2;   // 204.8 MB
    const size_t szHb   = (size_t)N_NODES * FEAT * 2;              // 12.8 MB
    const size_t szWt   = (size_t)NUM_RELS * FEAT * FEAT * 2;      // 128 KB
    const size_t szCnt  = (size_t)N_NODES * 4;
    const size_t szPayB = (size_t)N_NODES * CAP * 8;               // 51.2 MB
    const size_t szOvf  = (size_t)OVF_CAP * 16;                    // 1 MB
    const size_t szPayC = (size_t)N_EDGES * 8;                     // 25.6 MB (CSR)
    const size_t szOfs  = (size_t)(N_NODES + 1) * 4;

    const size_t needBucket = align256(szT) + align256(szHb) + align256(szWt)
                            + align256(szPayB) + align256(szCnt) + align256(256)
                            + align256(szOvf);
    const size_t needCsr    = align256(szT) + align256(szHb) + align256(szWt)
                            + align256(szPayC) + 3 * align256(szCnt)
                            + align256(szOfs) + 2 * align256(1024);

    const int n4h = N_NODES * FEAT / 4;
    const int nodesPerRange = (N_NODES + N_RANGES - 1) / N_RANGES;

    if (ws_size >= needBucket) {
        char* ws = (char*)d_ws; size_t off = 0;
        unsigned short* T    = (unsigned short*)(ws + off); off += align256(szT);
        unsigned short* hb   = (unsigned short*)(ws + off); off += align256(szHb);
        unsigned short* Wt   = (unsigned short*)(ws + off); off += align256(szWt);
        i32x2*          pay  = (i32x2*)         (ws + off); off += align256(szPayB);
        int*            cnt  = (int*)           (ws + off); off += align256(szCnt);
        int*            ovfc = (int*)           (ws + off); off += align256(256);
        i32x4*          ovf  = (i32x4*)         (ws + off); off += align256(szOvf);

        hipLaunchKernelGGL(cvt_h_kernel, dim3((n4h + 255) / 256), dim3(256), 0, stream,
                           (const float4*)h, (ushort4*)hb, n4h);
        hipLaunchKernelGGL(cvt_w_kernel, dim3(NUM_RELS * FEAT * FEAT / 256), dim3(256),
                           0, stream, W, Wt);
        hipMemsetAsync(cnt, 0, szCnt, stream);
        hipMemsetAsync(ovfc, 0, 256, stream);

        hipLaunchKernelGGL(gemm_T_kernel, dim3((N_NODES + 63) / 64), dim3(256), 0, stream,
                           hb, Wt, T);

        for (int rg = 0; rg < N_RANGES; ++rg) {
            const int lo = rg * nodesPerRange;
            const int hi = min(lo + nodesPerRange, N_NODES);
            hipLaunchKernelGGL(fill_bucket_kernel, dim3((N_EDGES + 255) / 256), dim3(256),
                               0, stream, src, dst, rel, norm, cnt, pay, ovfc, ovf, lo, hi);
        }

        hipLaunchKernelGGL(aggregate_bucket_kernel, dim3(N_NODES / 4), dim3(256), 0, stream,
                           T, pay, cnt, ovfc, ovf, out);
        return;
    }

    if (ws_size >= needCsr) {
        char* ws = (char*)d_ws; size_t off = 0;
        unsigned short* T   = (unsigned short*)(ws + off); off += align256(szT);
        unsigned short* hb  = (unsigned short*)(ws + off); off += align256(szHb);
        unsigned short* Wt  = (unsigned short*)(ws + off); off += align256(szWt);
        i32x2*          pay = (i32x2*)         (ws + off); off += align256(szPayC);
        int*            cnt = (int*)           (ws + off); off += align256(szCnt);
        int*            ofs = (int*)           (ws + off); off += align256(szOfs);
        int*            cur = (int*)           (ws + off); off += align256(szCnt);
        int*            btot= (int*)           (ws + off); off += align256(1024);
        int*            bbas= (int*)           (ws + off); off += align256(1024);

        hipLaunchKernelGGL(cvt_h_kernel, dim3((n4h + 255) / 256), dim3(256), 0, stream,
                           (const float4*)h, (ushort4*)hb, n4h);
        hipLaunchKernelGGL(cvt_w_kernel, dim3(NUM_RELS * FEAT * FEAT / 256), dim3(256),
                           0, stream, W, Wt);
        hipMemsetAsync(cnt, 0, szCnt, stream);
        hipLaunchKernelGGL(gemm_T_kernel, dim3((N_NODES + 63) / 64), dim3(256), 0, stream,
                           hb, Wt, T);
        hipLaunchKernelGGL(hist_kernel, dim3((N_EDGES + 255) / 256), dim3(256), 0, stream,
                           dst, cnt);
        const int nBlocksScan = (N_NODES + 1023) / 1024;
        hipLaunchKernelGGL(scan1_kernel, dim3(nBlocksScan), dim3(1024), 0, stream,
                           cnt, ofs, btot, N_NODES);
        hipLaunchKernelGGL(scan2_kernel, dim3(1), dim3(128), 0, stream,
                           btot, bbas, nBlocksScan);
        hipLaunchKernelGGL(scan3_kernel, dim3(nBlocksScan), dim3(1024), 0, stream,
                           ofs, cur, bbas, N_NODES);
        for (int rg = 0; rg < N_RANGES; ++rg) {
            const int lo = rg * nodesPerRange;
            const int hi = min(lo + nodesPerRange, N_NODES);
            hipLaunchKernelGGL(fill_kernel, dim3((N_EDGES + 255) / 256), dim3(256), 0, stream,
                               src, dst, rel, norm, cur, pay, lo, hi);
        }
        hipLaunchKernelGGL(aggregate_kernel, dim3(N_NODES / 4), dim3(256), 0, stream,
                           T, pay, ofs, out);
        return;
    }

    // last-resort atomic path
    hipMemsetAsync(d_out, 0, (size_t)out_size * sizeof(float), stream);
    hipLaunchKernelGGL(rgcn_edge_kernel, dim3(16 * 128), dim3(256), 0, stream,
                       h, W, norm, src, dst, rel, out);
    const int n4 = out_size / 4;
    hipLaunchKernelGGL(relu_kernel, dim3((n4 + 255) / 256), dim3(256), 0, stream,
                       (float4*)d_out, n4);
}

// Round 8
// 560.415 us; speedup vs baseline: 1.1297x; 1.0440x over previous
//
#include <hip/hip_runtime.h>

#define N_NODES 100000
#define N_EDGES 3200000
#define FEAT 64
#define NUM_RELS 16
#define CAP 64
#define OVF_CAP 65536
#define N_RANGES 8
#define NODES_PER_RANGE 12500   // N_NODES / N_RANGES exact
#define NCHUNKS 256
#define EDGES_PER_CHUNK 12500   // N_EDGES / NCHUNKS exact

typedef float f32x4 __attribute__((ext_vector_type(4)));
typedef float f32x16 __attribute__((ext_vector_type(16)));
typedef short s16x8 __attribute__((ext_vector_type(8)));
typedef int   i32x2 __attribute__((ext_vector_type(2)));
typedef int   i32x4 __attribute__((ext_vector_type(4)));

__device__ __forceinline__ unsigned short f32_to_bf16_rne(float x) {
    unsigned int u = __float_as_uint(x);
    unsigned int r = (u + 0x7fffu + ((u >> 16) & 1u)) >> 16;
    return (unsigned short)r;
}
__device__ __forceinline__ float bf16_to_f32(unsigned short s) {
    return __uint_as_float(((unsigned int)s) << 16);
}
// T offset (in shorts) for (node s, rel r): blocked layout [N/16][R][16][64]
__device__ __forceinline__ int t_offset(int s, int r) {
    return ((s >> 4) << 14) | (r << 10) | ((s & 15) << 6);
}

// ---------------- conversion kernels ----------------
__global__ __launch_bounds__(256) void cvt_h_kernel(const float4* __restrict__ h4,
                                                    ushort4* __restrict__ hb4, int n4)
{
    int i = blockIdx.x * 256 + threadIdx.x;
    if (i < n4) {
        float4 v = h4[i];
        ushort4 o;
        o.x = f32_to_bf16_rne(v.x); o.y = f32_to_bf16_rne(v.y);
        o.z = f32_to_bf16_rne(v.z); o.w = f32_to_bf16_rne(v.w);
        hb4[i] = o;
    }
}

// Wt[r][o][k] = bf16(W[r][k][o])
__global__ __launch_bounds__(256) void cvt_w_kernel(const float* __restrict__ W,
                                                    unsigned short* __restrict__ Wt)
{
    int t = blockIdx.x * 256 + threadIdx.x;          // 16*64*64 threads
    int r = t >> 12, o = (t >> 6) & 63, k = t & 63;
    Wt[t] = f32_to_bf16_rne(W[(r << 12) + (k << 6) + o]);
}

// ---------------- phase 1: dense transform, blocked T layout ----------------
// D = mfma(W_frag, h_frag): lane (q=lane&15,g4=lane>>4) holds node row0+q,
// feats t*16+g4*4+{0..3}. Stage the 16x64 tile in per-wave LDS, read back
// row-major, store 4x dwordx2 per rr = 4 contiguous 512-B runs (4 segments
// of 128 B each vs 16x32-B scatter -> 4x fewer L2 segment requests).
__global__ __launch_bounds__(256) void gemm_T_kernel(
    const unsigned short* __restrict__ hb,   // [N][64] bf16
    const unsigned short* __restrict__ Wt,   // [16][o][k] bf16
    unsigned short* __restrict__ T)          // [N/16][16][16][64] bf16
{
    __shared__ short lds[4][16][68];                 // stride 68 shorts = 136 B
    const int lane  = threadIdx.x & 63;
    const int w     = threadIdx.x >> 6;
    const int row0  = blockIdx.x * 64 + w * 16;      // this wave's 16 nodes
    if (row0 >= N_NODES) return;                     // N%16==0: full tiles only
    const int q     = lane & 15;
    const int g4    = lane >> 4;

    const unsigned short* ap = hb + ((size_t)(row0 + q) << 6) + (g4 << 3);
    const s16x8 a0 = *reinterpret_cast<const s16x8*>(ap);
    const s16x8 a1 = *reinterpret_cast<const s16x8*>(ap + 32);

    const unsigned short* wbase = Wt + ((size_t)q << 6) + (g4 << 3);
    unsigned short* tb = T + ((size_t)(row0 >> 4) << 14);
    const int nrd = lane >> 4;                       // read: node base
    const int c   = lane & 15;                       // read: 8-B chunk

    auto loadB = [&](s16x8* Bf, int r) {
        const unsigned short* wp = wbase + ((size_t)r << 12);
        #pragma unroll
        for (int t = 0; t < 4; ++t)
            #pragma unroll
            for (int kh = 0; kh < 2; ++kh)
                Bf[t * 2 + kh] = *reinterpret_cast<const s16x8*>(wp + (t << 10) + (kh << 5));
    };
    auto compStore = [&](const s16x8* Bf, int rr) {
        f32x4 acc[4] = {f32x4{0,0,0,0}, f32x4{0,0,0,0}, f32x4{0,0,0,0}, f32x4{0,0,0,0}};
        #pragma unroll
        for (int t = 0; t < 4; ++t) {
            acc[t] = __builtin_amdgcn_mfma_f32_16x16x32_bf16(Bf[t*2+0], a0, acc[t], 0, 0, 0);
            acc[t] = __builtin_amdgcn_mfma_f32_16x16x32_bf16(Bf[t*2+1], a1, acc[t], 0, 0, 0);
        }
        #pragma unroll
        for (int t = 0; t < 4; ++t) {
            i32x2 pk;
            pk.x = (int)((unsigned)f32_to_bf16_rne(acc[t][0]) |
                         ((unsigned)f32_to_bf16_rne(acc[t][1]) << 16));
            pk.y = (int)((unsigned)f32_to_bf16_rne(acc[t][2]) |
                         ((unsigned)f32_to_bf16_rne(acc[t][3]) << 16));
            *reinterpret_cast<i32x2*>(&lds[w][q][g4 * 4 + t * 16]) = pk;
        }
        // wave-sync: drain the 4 ds_writes; memory clobber pins ordering.
        asm volatile("s_waitcnt lgkmcnt(0)" ::: "memory");
        unsigned short* tr = tb + (rr << 10);
        #pragma unroll
        for (int j = 0; j < 4; ++j) {
            const int n = nrd + 4 * j;
            i32x2 v = *reinterpret_cast<const i32x2*>(&lds[w][n][c * 4]);
            *reinterpret_cast<i32x2*>(tr + (n << 6) + (c << 2)) = v;
        }
    };

    s16x8 B0[8], B1[8];
    loadB(B0, 0);
    #pragma unroll
    for (int rp = 0; rp < 16; rp += 2) {
        loadB(B1, rp + 1);
        compStore(B0, rp);
        if (rp + 2 < 16) loadB(B0, rp + 2);
        compStore(B1, rp + 1);
    }
}

// ---------------- phase 2: bucketed scatter, single launch -------------------
// range = bid & 7 (XCD round-robin -> per-XCD cnt/pay locality), chunk = bid>>3.
__global__ __launch_bounds__(256) void fill_bucket_kernel(
    const int* __restrict__ src, const int* __restrict__ dst,
    const int* __restrict__ rel, const float* __restrict__ norm,
    int* __restrict__ cnt, i32x2* __restrict__ pay,
    int* __restrict__ ovfc, i32x4* __restrict__ ovf)
{
    const int range = blockIdx.x & (N_RANGES - 1);
    const int chunk = blockIdx.x >> 3;
    const int lo = range * NODES_PER_RANGE;
    const int hi = lo + NODES_PER_RANGE;
    const int e0 = chunk * EDGES_PER_CHUNK;
    const int e1 = e0 + EDGES_PER_CHUNK;

    for (int e = e0 + threadIdx.x; e < e1; e += 256) {
        int d = __builtin_nontemporal_load(&dst[e]);
        if (d >= lo && d < hi) {
            int s   = src[e];
            int rl  = rel[e];
            float nv = norm[e];
            int tofs = t_offset(s, rl);
            int pos = atomicAdd(&cnt[d], 1);
            if (pos < CAP) {
                i32x2 p; p.x = tofs; p.y = __float_as_int(nv);
                pay[(size_t)d * CAP + pos] = p;
            } else {
                int op = atomicAdd(ovfc, 1);
                if (op < OVF_CAP) {
                    i32x4 o; o.x = d; o.y = tofs;
                    o.z = __float_as_int(nv); o.w = 0;
                    ovf[op] = o;
                }
            }
        }
    }
}

// ---------------- phase 3: per-dst gather/sum + relu -------------------------
__global__ __launch_bounds__(256) void aggregate_bucket_kernel(
    const unsigned short* __restrict__ T,    // blocked layout
    const i32x2* __restrict__ pay,           // [N][CAP] {t_offset, norm}
    const int* __restrict__ cnt,             // [N]
    const int* __restrict__ ovfc, const i32x4* __restrict__ ovf,
    float* __restrict__ out)                 // [N][64]
{
    const int lane = threadIdx.x & 63;
    const int d    = blockIdx.x * 4 + (threadIdx.x >> 6);   // grid covers N exactly

    const int degRaw = __builtin_amdgcn_readfirstlane(cnt[d]);
    const int deg    = min(degRaw, CAP);
    const i32x2* pp  = pay + (size_t)d * CAP;

    float acc = 0.f;
    int i = 0;
    for (; i + 4 <= deg; i += 4) {
        i32x2 p0 = __builtin_nontemporal_load(&pp[i]);
        i32x2 p1 = __builtin_nontemporal_load(&pp[i + 1]);
        i32x2 p2 = __builtin_nontemporal_load(&pp[i + 2]);
        i32x2 p3 = __builtin_nontemporal_load(&pp[i + 3]);
        const unsigned short t0 = T[(size_t)(unsigned)p0.x + lane];
        const unsigned short t1 = T[(size_t)(unsigned)p1.x + lane];
        const unsigned short t2 = T[(size_t)(unsigned)p2.x + lane];
        const unsigned short t3 = T[(size_t)(unsigned)p3.x + lane];
        acc = fmaf(__int_as_float(p0.y), bf16_to_f32(t0), acc);
        acc = fmaf(__int_as_float(p1.y), bf16_to_f32(t1), acc);
        acc = fmaf(__int_as_float(p2.y), bf16_to_f32(t2), acc);
        acc = fmaf(__int_as_float(p3.y), bf16_to_f32(t3), acc);
    }
    for (; i < deg; ++i) {
        i32x2 p = __builtin_nontemporal_load(&pp[i]);
        const unsigned short t = T[(size_t)(unsigned)p.x + lane];
        acc = fmaf(__int_as_float(p.y), bf16_to_f32(t), acc);
    }
    if (degRaw > CAP) {                       // exact overflow handling (rare)
        const int no = min(__builtin_amdgcn_readfirstlane(*ovfc), OVF_CAP);
        for (int j = 0; j < no; ++j) {
            i32x4 o = ovf[j];
            if (o.x == d) {
                const unsigned short t = T[(size_t)(unsigned)o.y + lane];
                acc = fmaf(__int_as_float(o.z), bf16_to_f32(t), acc);
            }
        }
    }
    out[((size_t)d << 6) + lane] = fmaxf(acc, 0.f);
}

// ================= CSR path (fallback if ws too small for buckets) ===========
__global__ __launch_bounds__(256) void hist_kernel(const int* __restrict__ dst,
                                                   int* __restrict__ cnt)
{
    int e = blockIdx.x * 256 + threadIdx.x;
    if (e < N_EDGES) atomicAdd(&cnt[__builtin_nontemporal_load(&dst[e])], 1);
}

__global__ __launch_bounds__(1024) void scan1_kernel(const int* __restrict__ cnt,
                                                     int* __restrict__ ofs,
                                                     int* __restrict__ btot, int n)
{
    __shared__ int tmp[1024];
    const int tid = threadIdx.x;
    const int i = blockIdx.x * 1024 + tid;
    int v = (i < n) ? cnt[i] : 0;
    tmp[tid] = v; __syncthreads();
    #pragma unroll
    for (int off = 1; off < 1024; off <<= 1) {
        int t = (tid >= off) ? tmp[tid - off] : 0;
        __syncthreads();
        tmp[tid] += t;
        __syncthreads();
    }
    if (i < n) ofs[i] = tmp[tid] - v;
    if (tid == 1023) btot[blockIdx.x] = tmp[tid];
}

__global__ __launch_bounds__(128) void scan2_kernel(int* __restrict__ btot,
                                                    int* __restrict__ bbase, int nb)
{
    __shared__ int tmp[128];
    const int tid = threadIdx.x;
    int v = (tid < nb) ? btot[tid] : 0;
    tmp[tid] = v; __syncthreads();
    #pragma unroll
    for (int off = 1; off < 128; off <<= 1) {
        int t = (tid >= off) ? tmp[tid - off] : 0;
        __syncthreads();
        tmp[tid] += t;
        __syncthreads();
    }
    if (tid < nb) bbase[tid] = tmp[tid] - v;
}

__global__ __launch_bounds__(1024) void scan3_kernel(int* __restrict__ ofs,
                                                     int* __restrict__ cur,
                                                     const int* __restrict__ bbase, int n)
{
    const int i = blockIdx.x * 1024 + threadIdx.x;
    if (i < n) {
        int o = ofs[i] + bbase[blockIdx.x];
        ofs[i] = o;
        cur[i] = o;
    }
    if (i == 0) ofs[n] = N_EDGES;
}

__global__ __launch_bounds__(256) void fill_kernel(const int* __restrict__ src,
                                                   const int* __restrict__ dst,
                                                   const int* __restrict__ rel,
                                                   const float* __restrict__ norm,
                                                   int* __restrict__ cur,
                                                   i32x2* __restrict__ pay,
                                                   int lo, int hi)
{
    int e = blockIdx.x * 256 + threadIdx.x;
    if (e < N_EDGES) {
        int d = __builtin_nontemporal_load(&dst[e]);
        if (d >= lo && d < hi) {
            int s  = src[e];
            int rl = rel[e];
            float nv = norm[e];
            int pos = atomicAdd(&cur[d], 1);
            i32x2 p; p.x = t_offset(s, rl); p.y = __float_as_int(nv);
            pay[pos] = p;
        }
    }
}

__global__ __launch_bounds__(256) void aggregate_kernel(
    const unsigned short* __restrict__ T,
    const i32x2* __restrict__ pay,
    const int* __restrict__ ofs,
    float* __restrict__ out)
{
    const int lane = threadIdx.x & 63;
    const int d    = blockIdx.x * 4 + (threadIdx.x >> 6);

    const int beg = __builtin_amdgcn_readfirstlane(ofs[d]);
    const int end = __builtin_amdgcn_readfirstlane(ofs[d + 1]);

    float acc = 0.f;
    int i = beg;
    for (; i + 4 <= end; i += 4) {
        i32x2 p0 = __builtin_nontemporal_load(&pay[i]);
        i32x2 p1 = __builtin_nontemporal_load(&pay[i + 1]);
        i32x2 p2 = __builtin_nontemporal_load(&pay[i + 2]);
        i32x2 p3 = __builtin_nontemporal_load(&pay[i + 3]);
        const unsigned short t0 = T[(size_t)(unsigned)p0.x + lane];
        const unsigned short t1 = T[(size_t)(unsigned)p1.x + lane];
        const unsigned short t2 = T[(size_t)(unsigned)p2.x + lane];
        const unsigned short t3 = T[(size_t)(unsigned)p3.x + lane];
        acc = fmaf(__int_as_float(p0.y), bf16_to_f32(t0), acc);
        acc = fmaf(__int_as_float(p1.y), bf16_to_f32(t1), acc);
        acc = fmaf(__int_as_float(p2.y), bf16_to_f32(t2), acc);
        acc = fmaf(__int_as_float(p3.y), bf16_to_f32(t3), acc);
    }
    for (; i < end; ++i) {
        i32x2 p = __builtin_nontemporal_load(&pay[i]);
        const unsigned short t = T[(size_t)(unsigned)p.x + lane];
        acc = fmaf(__int_as_float(p.y), bf16_to_f32(t), acc);
    }
    out[((size_t)d << 6) + lane] = fmaxf(acc, 0.f);
}

// ---------------- atomic fallback (no workspace) ----------------
__global__ __launch_bounds__(256) void rgcn_edge_kernel(
    const float* __restrict__ h, const float* __restrict__ W,
    const float* __restrict__ norm, const int* __restrict__ src,
    const int* __restrict__ dst, const int* __restrict__ rel,
    float* __restrict__ out)
{
    const int lane = threadIdx.x & 63;
    const int w    = threadIdx.x >> 6;
    const int r    = blockIdx.x & 15;
    const int inst = blockIdx.x >> 4;
    const int wavesPerRel = (gridDim.x >> 4) * 4;
    const int wi   = inst * 4 + w;

    float wreg[64];
    const float* Wr = W + (size_t)r * (FEAT * FEAT) + lane;
    #pragma unroll
    for (int d = 0; d < 64; ++d) wreg[d] = Wr[d * 64];

    const int nChunks = N_EDGES / 64;
    for (int c = wi; c < nChunks; c += wavesPerRel) {
        const int base = c * 64;
        unsigned long long m = __ballot(rel[base + lane] == r);
        while (m) {
            const int idx = __ffsll(m) - 1;
            m &= (m - 1);
            const int e = base + idx;
            const int se = __builtin_amdgcn_readfirstlane(src[e]);
            const int de = __builtin_amdgcn_readfirstlane(dst[e]);
            const float nv = __uint_as_float(
                __builtin_amdgcn_readfirstlane(__float_as_uint(norm[e])));
            const float* hp = h + ((size_t)se << 6);
            f32x16 ha, hb2, hc, hd;
            asm volatile(
                "s_load_dwordx16 %0, %4, 0x0\n\ts_load_dwordx16 %1, %4, 0x40\n\t"
                "s_load_dwordx16 %2, %4, 0x80\n\ts_load_dwordx16 %3, %4, 0xc0\n\t"
                "s_waitcnt lgkmcnt(0)"
                : "=&s"(ha), "=&s"(hb2), "=&s"(hc), "=&s"(hd) : "s"(hp));
            float a0 = 0.f, a1 = 0.f, a2 = 0.f, a3 = 0.f;
            #pragma unroll
            for (int j = 0; j < 16; ++j) {
                a0 = fmaf(ha[j], wreg[j], a0);       a1 = fmaf(hb2[j], wreg[16 + j], a1);
                a2 = fmaf(hc[j], wreg[32 + j], a2);  a3 = fmaf(hd[j], wreg[48 + j], a3);
            }
            unsafeAtomicAdd(&out[(size_t)de * FEAT + lane], ((a0 + a1) + (a2 + a3)) * nv);
        }
    }
}

__global__ __launch_bounds__(256) void relu_kernel(float4* __restrict__ out, int n4)
{
    int i = blockIdx.x * 256 + threadIdx.x;
    if (i < n4) {
        float4 v = out[i];
        v.x = fmaxf(v.x, 0.f); v.y = fmaxf(v.y, 0.f);
        v.z = fmaxf(v.z, 0.f); v.w = fmaxf(v.w, 0.f);
        out[i] = v;
    }
}

// ---------------- host ----------------
static inline size_t align256(size_t x) { return (x + 255) & ~(size_t)255; }

extern "C" void kernel_launch(void* const* d_in, const int* in_sizes, int n_in,
                              void* d_out, int out_size, void* d_ws, size_t ws_size,
                              hipStream_t stream)
{
    (void)in_sizes; (void)n_in;

    const float* h    = (const float*)d_in[0];
    const float* W    = (const float*)d_in[1];
    const float* norm = (const float*)d_in[2];
    const int*   src  = (const int*)d_in[3];
    const int*   dst  = (const int*)d_in[4];
    const int*   rel  = (const int*)d_in[5];
    float*       out  = (float*)d_out;

    const size_t szT    = (size_t)N_NODES * NUM_RELS * FEAT * 2;   // 204.8 MB
    const size_t szHb   = (size_t)N_NODES * FEAT * 2;              // 12.8 MB
    const size_t szWt   = (size_t)NUM_RELS * FEAT * FEAT * 2;      // 128 KB
    const size_t szCnt  = (size_t)N_NODES * 4;
    const size_t szPayB = (size_t)N_NODES * CAP * 8;               // 51.2 MB
    const size_t szOvf  = (size_t)OVF_CAP * 16;                    // 1 MB
    const size_t szPayC = (size_t)N_EDGES * 8;                     // 25.6 MB (CSR)
    const size_t szOfs  = (size_t)(N_NODES + 1) * 4;

    const size_t needBucket = align256(szT) + align256(szHb) + align256(szWt)
                            + align256(szPayB) + align256(szCnt) + align256(256)
                            + align256(szOvf);
    const size_t needCsr    = align256(szT) + align256(szHb) + align256(szWt)
                            + align256(szPayC) + 3 * align256(szCnt)
                            + align256(szOfs) + 2 * align256(1024);

    const int n4h = N_NODES * FEAT / 4;

    if (ws_size >= needBucket) {
        char* ws = (char*)d_ws; size_t off = 0;
        unsigned short* T    = (unsigned short*)(ws + off); off += align256(szT);
        unsigned short* hb   = (unsigned short*)(ws + off); off += align256(szHb);
        unsigned short* Wt   = (unsigned short*)(ws + off); off += align256(szWt);
        i32x2*          pay  = (i32x2*)         (ws + off); off += align256(szPayB);
        int*            cnt  = (int*)           (ws + off); off += align256(szCnt);
        int*            ovfc = (int*)           (ws + off); off += align256(256);
        i32x4*          ovf  = (i32x4*)         (ws + off); off += align256(szOvf);

        hipLaunchKernelGGL(cvt_h_kernel, dim3((n4h + 255) / 256), dim3(256), 0, stream,
                           (const float4*)h, (ushort4*)hb, n4h);
        hipLaunchKernelGGL(cvt_w_kernel, dim3(NUM_RELS * FEAT * FEAT / 256), dim3(256),
                           0, stream, W, Wt);
        hipMemsetAsync(cnt, 0, szCnt, stream);
        hipMemsetAsync(ovfc, 0, 256, stream);

        hipLaunchKernelGGL(gemm_T_kernel, dim3((N_NODES + 63) / 64), dim3(256), 0, stream,
                           hb, Wt, T);

        hipLaunchKernelGGL(fill_bucket_kernel, dim3(NCHUNKS * N_RANGES), dim3(256),
                           0, stream, src, dst, rel, norm, cnt, pay, ovfc, ovf);

        hipLaunchKernelGGL(aggregate_bucket_kernel, dim3(N_NODES / 4), dim3(256), 0, stream,
                           T, pay, cnt, ovfc, ovf, out);
        return;
    }

    if (ws_size >= needCsr) {
        char* ws = (char*)d_ws; size_t off = 0;
        unsigned short* T   = (unsigned short*)(ws + off); off += align256(szT);
        unsigned short* hb  = (unsigned short*)(ws + off); off += align256(szHb);
        unsigned short* Wt  = (unsigned short*)(ws + off); off += align256(szWt);
        i32x2*          pay = (i32x2*)         (ws + off); off += align256(szPayC);
        int*            cnt = (int*)           (ws + off); off += align256(szCnt);
        int*            ofs = (int*)           (ws + off); off += align256(szOfs);
        int*            cur = (int*)           (ws + off); off += align256(szCnt);
        int*            btot= (int*)           (ws + off); off += align256(1024);
        int*            bbas= (int*)           (ws + off); off += align256(1024);

        hipLaunchKernelGGL(cvt_h_kernel, dim3((n4h + 255) / 256), dim3(256), 0, stream,
                           (const float4*)h, (ushort4*)hb, n4h);
        hipLaunchKernelGGL(cvt_w_kernel, dim3(NUM_RELS * FEAT * FEAT / 256), dim3(256),
                           0, stream, W, Wt);
        hipMemsetAsync(cnt, 0, szCnt, stream);
        hipLaunchKernelGGL(gemm_T_kernel, dim3((N_NODES + 63) / 64), dim3(256), 0, stream,
                           hb, Wt, T);
        hipLaunchKernelGGL(hist_kernel, dim3((N_EDGES + 255) / 256), dim3(256), 0, stream,
                           dst, cnt);
        const int nBlocksScan = (N_NODES + 1023) / 1024;
        hipLaunchKernelGGL(scan1_kernel, dim3(nBlocksScan), dim3(1024), 0, stream,
                           cnt, ofs, btot, N_NODES);
        hipLaunchKernelGGL(scan2_kernel, dim3(1), dim3(128), 0, stream,
                           btot, bbas, nBlocksScan);
        hipLaunchKernelGGL(scan3_kernel, dim3(nBlocksScan), dim3(1024), 0, stream,
                           ofs, cur, bbas, N_NODES);
        const int nodesPerRange = (N_NODES + N_RANGES - 1) / N_RANGES;
        for (int rg = 0; rg < N_RANGES; ++rg) {
            const int lo = rg * nodesPerRange;
            const int hi = min(lo + nodesPerRange, N_NODES);
            hipLaunchKernelGGL(fill_kernel, dim3((N_EDGES + 255) / 256), dim3(256), 0, stream,
                               src, dst, rel, norm, cur, pay, lo, hi);
        }
        hipLaunchKernelGGL(aggregate_kernel, dim3(N_NODES / 4), dim3(256), 0, stream,
                           T, pay, ofs, out);
        return;
    }

    // last-resort atomic path
    hipMemsetAsync(d_out, 0, (size_t)out_size * sizeof(float), stream);
    hipLaunchKernelGGL(rgcn_edge_kernel, dim3(16 * 128), dim3(256), 0, stream,
                       h, W, norm, src, dst, rel, out);
    const int n4 = out_size / 4;
    hipLaunchKernelGGL(relu_kernel, dim3((n4 + 255) / 256), dim3(256), 0, stream,
                       (float4*)d_out, n4);
}

// Round 9
// 434.555 us; speedup vs baseline: 1.4569x; 1.2896x over previous
//
#include <hip/hip_runtime.h>

#define N_NODES 100000
#define N_EDGES 3200000
#define FEAT 64
#define NUM_RELS 16
#define CAP 64
#define OVF_CAP 32768
#define RANGES_W 4
#define NODES_PER_W 25000       // N_NODES / RANGES_W exact
#define FILL_BLOCKS 1024
#define AGG_BLOCKS (NODES_PER_W / 4)   // 6250

typedef float f32x4 __attribute__((ext_vector_type(4)));
typedef float f32x16 __attribute__((ext_vector_type(16)));
typedef short s16x8 __attribute__((ext_vector_type(8)));
typedef int   i32x2 __attribute__((ext_vector_type(2)));
typedef int   i32x4 __attribute__((ext_vector_type(4)));

__device__ __forceinline__ unsigned short f32_to_bf16_rne(float x) {
    unsigned int u = __float_as_uint(x);
    unsigned int r = (u + 0x7fffu + ((u >> 16) & 1u)) >> 16;
    return (unsigned short)r;
}
__device__ __forceinline__ float bf16_to_f32(unsigned short s) {
    return __uint_as_float(((unsigned int)s) << 16);
}
// T offset (in shorts) for (node s, rel r): blocked layout [N/16][R][16][64]
__device__ __forceinline__ int t_offset(int s, int r) {
    return ((s >> 4) << 14) | (r << 10) | ((s & 15) << 6);
}

// ---------------- conversion kernels ----------------
__global__ __launch_bounds__(256) void cvt_h_kernel(const float4* __restrict__ h4,
                                                    ushort4* __restrict__ hb4, int n4)
{
    int i = blockIdx.x * 256 + threadIdx.x;
    if (i < n4) {
        float4 v = h4[i];
        ushort4 o;
        o.x = f32_to_bf16_rne(v.x); o.y = f32_to_bf16_rne(v.y);
        o.z = f32_to_bf16_rne(v.z); o.w = f32_to_bf16_rne(v.w);
        hb4[i] = o;
    }
}

// Wt[r][o][k] = bf16(W[r][k][o])
__global__ __launch_bounds__(256) void cvt_w_kernel(const float* __restrict__ W,
                                                    unsigned short* __restrict__ Wt)
{
    int t = blockIdx.x * 256 + threadIdx.x;          // 16*64*64 threads
    int r = t >> 12, o = (t >> 6) & 63, k = t & 63;
    Wt[t] = f32_to_bf16_rne(W[(r << 12) + (k << 6) + o]);
}

// ---------------- phase 1: dense transform, blocked T layout ----------------
__global__ __launch_bounds__(256) void gemm_T_kernel(
    const unsigned short* __restrict__ hb,   // [N][64] bf16
    const unsigned short* __restrict__ Wt,   // [16][o][k] bf16
    unsigned short* __restrict__ T)          // [N/16][16][16][64] bf16
{
    __shared__ short lds[4][16][68];                 // stride 68 shorts = 136 B
    const int lane  = threadIdx.x & 63;
    const int w     = threadIdx.x >> 6;
    const int row0  = blockIdx.x * 64 + w * 16;      // this wave's 16 nodes
    if (row0 >= N_NODES) return;                     // N%16==0: full tiles only
    const int q     = lane & 15;
    const int g4    = lane >> 4;

    const unsigned short* ap = hb + ((size_t)(row0 + q) << 6) + (g4 << 3);
    const s16x8 a0 = *reinterpret_cast<const s16x8*>(ap);
    const s16x8 a1 = *reinterpret_cast<const s16x8*>(ap + 32);

    const unsigned short* wbase = Wt + ((size_t)q << 6) + (g4 << 3);
    unsigned short* tb = T + ((size_t)(row0 >> 4) << 14);
    const int nrd = lane >> 4;                       // read: node base
    const int c   = lane & 15;                       // read: 8-B chunk

    auto loadB = [&](s16x8* Bf, int r) {
        const unsigned short* wp = wbase + ((size_t)r << 12);
        #pragma unroll
        for (int t = 0; t < 4; ++t)
            #pragma unroll
            for (int kh = 0; kh < 2; ++kh)
                Bf[t * 2 + kh] = *reinterpret_cast<const s16x8*>(wp + (t << 10) + (kh << 5));
    };
    auto compStore = [&](const s16x8* Bf, int rr) {
        f32x4 acc[4] = {f32x4{0,0,0,0}, f32x4{0,0,0,0}, f32x4{0,0,0,0}, f32x4{0,0,0,0}};
        #pragma unroll
        for (int t = 0; t < 4; ++t) {
            acc[t] = __builtin_amdgcn_mfma_f32_16x16x32_bf16(Bf[t*2+0], a0, acc[t], 0, 0, 0);
            acc[t] = __builtin_amdgcn_mfma_f32_16x16x32_bf16(Bf[t*2+1], a1, acc[t], 0, 0, 0);
        }
        #pragma unroll
        for (int t = 0; t < 4; ++t) {
            i32x2 pk;
            pk.x = (int)((unsigned)f32_to_bf16_rne(acc[t][0]) |
                         ((unsigned)f32_to_bf16_rne(acc[t][1]) << 16));
            pk.y = (int)((unsigned)f32_to_bf16_rne(acc[t][2]) |
                         ((unsigned)f32_to_bf16_rne(acc[t][3]) << 16));
            *reinterpret_cast<i32x2*>(&lds[w][q][g4 * 4 + t * 16]) = pk;
        }
        asm volatile("s_waitcnt lgkmcnt(0)" ::: "memory");   // per-wave LDS drain
        unsigned short* tr = tb + (rr << 10);
        #pragma unroll
        for (int j = 0; j < 4; ++j) {
            const int n = nrd + 4 * j;
            i32x2 v = *reinterpret_cast<const i32x2*>(&lds[w][n][c * 4]);
            *reinterpret_cast<i32x2*>(tr + (n << 6) + (c << 2)) = v;
        }
    };

    s16x8 B0[8], B1[8];
    loadB(B0, 0);
    #pragma unroll
    for (int rp = 0; rp < 16; rp += 2) {
        loadB(B1, rp + 1);
        compStore(B0, rp);
        if (rp + 2 < 16) loadB(B0, rp + 2);
        compStore(B1, rp + 1);
    }
}

// -------- phases 2+3 fused: windowed bucket scatter + per-dst aggregate ------
// One launch carries two block roles: blocks [0,FILL_BLOCKS) fill range
// fillRange into window payF; remaining AGG_BLOCKS blocks aggregate range
// aggRange from window payG (filled by the PREVIOUS launch; stream order is
// the dependency). Windows double-buffer: 2 x 25K nodes x CAP x 8 B.
__global__ __launch_bounds__(256) void fill_agg_kernel(
    const int* __restrict__ src, const int* __restrict__ dst,
    const int* __restrict__ rel, const float* __restrict__ norm,
    int* __restrict__ cnt, int* __restrict__ ovfc, i32x4* __restrict__ ovf,
    i32x2* __restrict__ payF, const i32x2* __restrict__ payG,
    const unsigned short* __restrict__ T, float* __restrict__ out,
    int fillRange, int aggRange)
{
    const int nFill = (fillRange >= 0) ? FILL_BLOCKS : 0;
    if ((int)blockIdx.x < nFill) {
        // ---- fill role ----
        const int lo = fillRange * NODES_PER_W, hi = lo + NODES_PER_W;
        for (int e = blockIdx.x * 256 + threadIdx.x; e < N_EDGES; e += nFill * 256) {
            int d = __builtin_nontemporal_load(&dst[e]);
            if (d >= lo && d < hi) {
                int s   = __builtin_nontemporal_load(&src[e]);
                int rl  = __builtin_nontemporal_load(&rel[e]);
                float nv = __builtin_nontemporal_load(&norm[e]);
                int tofs = t_offset(s, rl);
                int pos = atomicAdd(&cnt[d], 1);
                if (pos < CAP) {
                    i32x2 p; p.x = tofs; p.y = __float_as_int(nv);
                    payF[(size_t)(d - lo) * CAP + pos] = p;
                } else {
                    int op = atomicAdd(ovfc, 1);
                    if (op < OVF_CAP) {
                        i32x4 o; o.x = d; o.y = tofs;
                        o.z = __float_as_int(nv); o.w = 0;
                        ovf[op] = o;
                    }
                }
            }
        }
    } else {
        // ---- aggregate role ----
        const int b    = blockIdx.x - nFill;
        const int lo   = aggRange * NODES_PER_W;
        const int lane = threadIdx.x & 63;
        const int d    = lo + b * 4 + (threadIdx.x >> 6);

        const int degRaw = __builtin_amdgcn_readfirstlane(cnt[d]);
        const int deg    = min(degRaw, CAP);
        const i32x2* pp  = payG + (size_t)(d - lo) * CAP;

        float acc = 0.f;
        int i = 0;
        for (; i + 4 <= deg; i += 4) {
            i32x2 p0 = __builtin_nontemporal_load(&pp[i]);
            i32x2 p1 = __builtin_nontemporal_load(&pp[i + 1]);
            i32x2 p2 = __builtin_nontemporal_load(&pp[i + 2]);
            i32x2 p3 = __builtin_nontemporal_load(&pp[i + 3]);
            const unsigned short t0 = T[(size_t)(unsigned)p0.x + lane];
            const unsigned short t1 = T[(size_t)(unsigned)p1.x + lane];
            const unsigned short t2 = T[(size_t)(unsigned)p2.x + lane];
            const unsigned short t3 = T[(size_t)(unsigned)p3.x + lane];
            acc = fmaf(__int_as_float(p0.y), bf16_to_f32(t0), acc);
            acc = fmaf(__int_as_float(p1.y), bf16_to_f32(t1), acc);
            acc = fmaf(__int_as_float(p2.y), bf16_to_f32(t2), acc);
            acc = fmaf(__int_as_float(p3.y), bf16_to_f32(t3), acc);
        }
        for (; i < deg; ++i) {
            i32x2 p = __builtin_nontemporal_load(&pp[i]);
            const unsigned short t = T[(size_t)(unsigned)p.x + lane];
            acc = fmaf(__int_as_float(p.y), bf16_to_f32(t), acc);
        }
        if (degRaw > CAP) {                      // exact overflow handling (rare)
            const int no = min(__builtin_amdgcn_readfirstlane(*ovfc), OVF_CAP);
            for (int j = 0; j < no; ++j) {
                i32x4 o = ovf[j];
                if (o.x == d) {
                    const unsigned short t = T[(size_t)(unsigned)o.y + lane];
                    acc = fmaf(__int_as_float(o.z), bf16_to_f32(t), acc);
                }
            }
        }
        out[((size_t)d << 6) + lane] = fmaxf(acc, 0.f);
    }
}

// ---------------- atomic fallback (no workspace) ----------------
__global__ __launch_bounds__(256) void rgcn_edge_kernel(
    const float* __restrict__ h, const float* __restrict__ W,
    const float* __restrict__ norm, const int* __restrict__ src,
    const int* __restrict__ dst, const int* __restrict__ rel,
    float* __restrict__ out)
{
    const int lane = threadIdx.x & 63;
    const int w    = threadIdx.x >> 6;
    const int r    = blockIdx.x & 15;
    const int inst = blockIdx.x >> 4;
    const int wavesPerRel = (gridDim.x >> 4) * 4;
    const int wi   = inst * 4 + w;

    float wreg[64];
    const float* Wr = W + (size_t)r * (FEAT * FEAT) + lane;
    #pragma unroll
    for (int d = 0; d < 64; ++d) wreg[d] = Wr[d * 64];

    const int nChunks = N_EDGES / 64;
    for (int c = wi; c < nChunks; c += wavesPerRel) {
        const int base = c * 64;
        unsigned long long m = __ballot(rel[base + lane] == r);
        while (m) {
            const int idx = __ffsll(m) - 1;
            m &= (m - 1);
            const int e = base + idx;
            const int se = __builtin_amdgcn_readfirstlane(src[e]);
            const int de = __builtin_amdgcn_readfirstlane(dst[e]);
            const float nv = __uint_as_float(
                __builtin_amdgcn_readfirstlane(__float_as_uint(norm[e])));
            const float* hp = h + ((size_t)se << 6);
            f32x16 ha, hb2, hc, hd;
            asm volatile(
                "s_load_dwordx16 %0, %4, 0x0\n\ts_load_dwordx16 %1, %4, 0x40\n\t"
                "s_load_dwordx16 %2, %4, 0x80\n\ts_load_dwordx16 %3, %4, 0xc0\n\t"
                "s_waitcnt lgkmcnt(0)"
                : "=&s"(ha), "=&s"(hb2), "=&s"(hc), "=&s"(hd) : "s"(hp));
            float a0 = 0.f, a1 = 0.f, a2 = 0.f, a3 = 0.f;
            #pragma unroll
            for (int j = 0; j < 16; ++j) {
                a0 = fmaf(ha[j], wreg[j], a0);       a1 = fmaf(hb2[j], wreg[16 + j], a1);
                a2 = fmaf(hc[j], wreg[32 + j], a2);  a3 = fmaf(hd[j], wreg[48 + j], a3);
            }
            unsafeAtomicAdd(&out[(size_t)de * FEAT + lane], ((a0 + a1) + (a2 + a3)) * nv);
        }
    }
}

__global__ __launch_bounds__(256) void relu_kernel(float4* __restrict__ out, int n4)
{
    int i = blockIdx.x * 256 + threadIdx.x;
    if (i < n4) {
        float4 v = out[i];
        v.x = fmaxf(v.x, 0.f); v.y = fmaxf(v.y, 0.f);
        v.z = fmaxf(v.z, 0.f); v.w = fmaxf(v.w, 0.f);
        out[i] = v;
    }
}

// ---------------- host ----------------
static inline size_t align256(size_t x) { return (x + 255) & ~(size_t)255; }

extern "C" void kernel_launch(void* const* d_in, const int* in_sizes, int n_in,
                              void* d_out, int out_size, void* d_ws, size_t ws_size,
                              hipStream_t stream)
{
    (void)in_sizes; (void)n_in;

    const float* h    = (const float*)d_in[0];
    const float* W    = (const float*)d_in[1];
    const float* norm = (const float*)d_in[2];
    const int*   src  = (const int*)d_in[3];
    const int*   dst  = (const int*)d_in[4];
    const int*   rel  = (const int*)d_in[5];
    float*       out  = (float*)d_out;

    const size_t szT    = (size_t)N_NODES * NUM_RELS * FEAT * 2;   // 204.8 MB
    const size_t szHb   = (size_t)N_NODES * FEAT * 2;              // 12.8 MB
    const size_t szWt   = (size_t)NUM_RELS * FEAT * FEAT * 2;      // 128 KB
    const size_t szCnt  = (size_t)N_NODES * 4;                     // 400 KB
    const size_t szPayW = (size_t)NODES_PER_W * CAP * 8;           // 12.8 MB per window
    const size_t szOvf  = (size_t)OVF_CAP * 16;                    // 512 KB

    const size_t needWin = align256(szT) + align256(szHb) + align256(szWt)
                         + 2 * align256(szPayW) + align256(szCnt) + align256(256)
                         + align256(szOvf);                        // ~244.3 MB

    const int n4h = N_NODES * FEAT / 4;

    if (ws_size >= needWin) {
        char* ws = (char*)d_ws; size_t off = 0;
        unsigned short* T    = (unsigned short*)(ws + off); off += align256(szT);
        unsigned short* hb   = (unsigned short*)(ws + off); off += align256(szHb);
        unsigned short* Wt   = (unsigned short*)(ws + off); off += align256(szWt);
        i32x2*          pay0 = (i32x2*)         (ws + off); off += align256(szPayW);
        i32x2*          pay1 = (i32x2*)         (ws + off); off += align256(szPayW);
        int*            cnt  = (int*)           (ws + off); off += align256(szCnt);
        int*            ovfc = (int*)           (ws + off); off += align256(256);
        i32x4*          ovf  = (i32x4*)         (ws + off); off += align256(szOvf);

        hipLaunchKernelGGL(cvt_h_kernel, dim3((n4h + 255) / 256), dim3(256), 0, stream,
                           (const float4*)h, (ushort4*)hb, n4h);
        hipLaunchKernelGGL(cvt_w_kernel, dim3(NUM_RELS * FEAT * FEAT / 256), dim3(256),
                           0, stream, W, Wt);
        hipMemsetAsync(cnt, 0, szCnt, stream);
        hipMemsetAsync(ovfc, 0, 256, stream);

        hipLaunchKernelGGL(gemm_T_kernel, dim3((N_NODES + 63) / 64), dim3(256), 0, stream,
                           hb, Wt, T);

        // Pipelined: K0 fill(0); K1 fill(1)+agg(0); K2 fill(2)+agg(1);
        //            K3 fill(3)+agg(2); K4 agg(3). Windows alternate 0,1,0,1.
        i32x2* win[2] = {pay0, pay1};
        hipLaunchKernelGGL(fill_agg_kernel, dim3(FILL_BLOCKS), dim3(256), 0, stream,
                           src, dst, rel, norm, cnt, ovfc, ovf,
                           win[0], (const i32x2*)nullptr, T, out, 0, -1);
        for (int r = 1; r < RANGES_W; ++r) {
            hipLaunchKernelGGL(fill_agg_kernel, dim3(FILL_BLOCKS + AGG_BLOCKS), dim3(256),
                               0, stream, src, dst, rel, norm, cnt, ovfc, ovf,
                               win[r & 1], win[(r - 1) & 1], T, out, r, r - 1);
        }
        hipLaunchKernelGGL(fill_agg_kernel, dim3(AGG_BLOCKS), dim3(256), 0, stream,
                           src, dst, rel, norm, cnt, ovfc, ovf,
                           (i32x2*)nullptr, win[(RANGES_W - 1) & 1], T, out,
                           -1, RANGES_W - 1);
        return;
    }

    // last-resort atomic path
    hipMemsetAsync(d_out, 0, (size_t)out_size * sizeof(float), stream);
    hipLaunchKernelGGL(rgcn_edge_kernel, dim3(16 * 128), dim3(256), 0, stream,
                       h, W, norm, src, dst, rel, out);
    const int n4 = out_size / 4;
    hipLaunchKernelGGL(relu_kernel, dim3((n4 + 255) / 256), dim3(256), 0, stream,
                       (float4*)d_out, n4);
}

// Round 10
// 425.402 us; speedup vs baseline: 1.4882x; 1.0215x over previous
//
#include <hip/hip_runtime.h>

#define N_NODES 100000
#define N_EDGES 3200000
#define FEAT 64
#define NUM_RELS 16
#define CAP 64
#define OVF_CAP 32768
#define RANGES_W 4
#define NODES_PER_W 25000       // N_NODES / RANGES_W exact
#define FILL_BLOCKS 1024
#define AGG_BLOCKS (NODES_PER_W / 4)   // 6250
#define NODE_TILES 1563         // ceil(N_NODES / 64)
#define NGEMM (NODE_TILES * 4)  // gemm blocks in fused launch (4 rel-groups)

typedef float f32x4 __attribute__((ext_vector_type(4)));
typedef float f32x16 __attribute__((ext_vector_type(16)));
typedef short s16x8 __attribute__((ext_vector_type(8)));
typedef int   i32x2 __attribute__((ext_vector_type(2)));
typedef int   i32x4 __attribute__((ext_vector_type(4)));

__device__ __forceinline__ unsigned short f32_to_bf16_rne(float x) {
    unsigned int u = __float_as_uint(x);
    unsigned int r = (u + 0x7fffu + ((u >> 16) & 1u)) >> 16;
    return (unsigned short)r;
}
__device__ __forceinline__ float bf16_to_f32(unsigned short s) {
    return __uint_as_float(((unsigned int)s) << 16);
}
// T offset (in shorts) for (node s, rel r): blocked layout [N/16][R][16][64]
__device__ __forceinline__ int t_offset(int s, int r) {
    return ((s >> 4) << 14) | (r << 10) | ((s & 15) << 6);
}

// ---------------- conversion kernels ----------------
__global__ __launch_bounds__(256) void cvt_h_kernel(const float4* __restrict__ h4,
                                                    ushort4* __restrict__ hb4, int n4)
{
    int i = blockIdx.x * 256 + threadIdx.x;
    if (i < n4) {
        float4 v = h4[i];
        ushort4 o;
        o.x = f32_to_bf16_rne(v.x); o.y = f32_to_bf16_rne(v.y);
        o.z = f32_to_bf16_rne(v.z); o.w = f32_to_bf16_rne(v.w);
        hb4[i] = o;
    }
}

// Wt[r][o][k] = bf16(W[r][k][o])
__global__ __launch_bounds__(256) void cvt_w_kernel(const float* __restrict__ W,
                                                    unsigned short* __restrict__ Wt)
{
    int t = blockIdx.x * 256 + threadIdx.x;          // 16*64*64 threads
    int r = t >> 12, o = (t >> 6) & 63, k = t & 63;
    Wt[t] = f32_to_bf16_rne(W[(r << 12) + (k << 6) + o]);
}

// ---- fused phase 1 + fill(range 0): gemm split over 4 rel-groups -----------
// Blocks [0,NGEMM): node tile (bid>>2), rel group (bid&3) -> 4 rels per wave.
// 25K waves (vs 6252) hide store latency. Blocks [NGEMM, +FILL_BLOCKS): fill
// range 0 (independent of T; stream order covers K1's agg(0) dependency).
__global__ __launch_bounds__(256) void gemm_fill_kernel(
    const unsigned short* __restrict__ hb,   // [N][64] bf16
    const unsigned short* __restrict__ Wt,   // [16][o][k] bf16
    unsigned short* __restrict__ T,          // [N/16][16][16][64] bf16
    const int* __restrict__ src, const int* __restrict__ dst,
    const int* __restrict__ rel, const float* __restrict__ norm,
    int* __restrict__ cnt, int* __restrict__ ovfc, i32x4* __restrict__ ovf,
    i32x2* __restrict__ payF)
{
    if ((int)blockIdx.x >= NGEMM) {
        // ---- fill role: range 0 ----
        const int b = blockIdx.x - NGEMM;
        for (int e = b * 256 + threadIdx.x; e < N_EDGES; e += FILL_BLOCKS * 256) {
            int d = __builtin_nontemporal_load(&dst[e]);
            if (d < NODES_PER_W) {
                int s   = __builtin_nontemporal_load(&src[e]);
                int rl  = __builtin_nontemporal_load(&rel[e]);
                float nv = __builtin_nontemporal_load(&norm[e]);
                int tofs = t_offset(s, rl);
                int pos = atomicAdd(&cnt[d], 1);
                if (pos < CAP) {
                    i32x2 p; p.x = tofs; p.y = __float_as_int(nv);
                    payF[(size_t)d * CAP + pos] = p;
                } else {
                    int op = atomicAdd(ovfc, 1);
                    if (op < OVF_CAP) {
                        i32x4 o; o.x = d; o.y = tofs;
                        o.z = __float_as_int(nv); o.w = 0;
                        ovf[op] = o;
                    }
                }
            }
        }
        return;
    }

    // ---- gemm role ----
    __shared__ short lds[4][16][68];                 // per-wave 16x64 tile, stride 68
    const int lane  = threadIdx.x & 63;
    const int w     = threadIdx.x >> 6;
    const int tile  = blockIdx.x >> 2;
    const int rg    = blockIdx.x & 3;                // rel group: rels rg*4..rg*4+3
    const int row0  = tile * 64 + w * 16;
    if (row0 >= N_NODES) return;                     // N%16==0: full tiles only
    const int q     = lane & 15;
    const int g4    = lane >> 4;

    const unsigned short* ap = hb + ((size_t)(row0 + q) << 6) + (g4 << 3);
    const s16x8 a0 = *reinterpret_cast<const s16x8*>(ap);
    const s16x8 a1 = *reinterpret_cast<const s16x8*>(ap + 32);

    const unsigned short* wbase = Wt + ((size_t)q << 6) + (g4 << 3);
    unsigned short* tb = T + ((size_t)(row0 >> 4) << 14);
    const int nrd = lane >> 4;
    const int c   = lane & 15;

    auto loadB = [&](s16x8* Bf, int r) {
        const unsigned short* wp = wbase + ((size_t)r << 12);
        #pragma unroll
        for (int t = 0; t < 4; ++t)
            #pragma unroll
            for (int kh = 0; kh < 2; ++kh)
                Bf[t * 2 + kh] = *reinterpret_cast<const s16x8*>(wp + (t << 10) + (kh << 5));
    };
    auto compStore = [&](const s16x8* Bf, int rr) {
        f32x4 acc[4] = {f32x4{0,0,0,0}, f32x4{0,0,0,0}, f32x4{0,0,0,0}, f32x4{0,0,0,0}};
        #pragma unroll
        for (int t = 0; t < 4; ++t) {
            acc[t] = __builtin_amdgcn_mfma_f32_16x16x32_bf16(Bf[t*2+0], a0, acc[t], 0, 0, 0);
            acc[t] = __builtin_amdgcn_mfma_f32_16x16x32_bf16(Bf[t*2+1], a1, acc[t], 0, 0, 0);
        }
        #pragma unroll
        for (int t = 0; t < 4; ++t) {
            i32x2 pk;
            pk.x = (int)((unsigned)f32_to_bf16_rne(acc[t][0]) |
                         ((unsigned)f32_to_bf16_rne(acc[t][1]) << 16));
            pk.y = (int)((unsigned)f32_to_bf16_rne(acc[t][2]) |
                         ((unsigned)f32_to_bf16_rne(acc[t][3]) << 16));
            *reinterpret_cast<i32x2*>(&lds[w][q][g4 * 4 + t * 16]) = pk;
        }
        asm volatile("s_waitcnt lgkmcnt(0)" ::: "memory");   // per-wave LDS drain
        unsigned short* tr = tb + (rr << 10);
        #pragma unroll
        for (int j = 0; j < 4; ++j) {
            const int n = nrd + 4 * j;
            i32x2 v = *reinterpret_cast<const i32x2*>(&lds[w][n][c * 4]);
            *reinterpret_cast<i32x2*>(tr + (n << 6) + (c << 2)) = v;
        }
    };

    const int r0 = rg * 4;
    s16x8 B0[8], B1[8];
    loadB(B0, r0);
    loadB(B1, r0 + 1);
    compStore(B0, r0);
    loadB(B0, r0 + 2);
    compStore(B1, r0 + 1);
    loadB(B1, r0 + 3);
    compStore(B0, r0 + 2);
    compStore(B1, r0 + 3);
}

// -------- phases 2+3 fused: windowed bucket scatter + per-dst aggregate ------
__global__ __launch_bounds__(256) void fill_agg_kernel(
    const int* __restrict__ src, const int* __restrict__ dst,
    const int* __restrict__ rel, const float* __restrict__ norm,
    int* __restrict__ cnt, int* __restrict__ ovfc, i32x4* __restrict__ ovf,
    i32x2* __restrict__ payF, const i32x2* __restrict__ payG,
    const unsigned short* __restrict__ T, float* __restrict__ out,
    int fillRange, int aggRange)
{
    const int nFill = (fillRange >= 0) ? FILL_BLOCKS : 0;
    if ((int)blockIdx.x < nFill) {
        // ---- fill role ----
        const int lo = fillRange * NODES_PER_W, hi = lo + NODES_PER_W;
        for (int e = blockIdx.x * 256 + threadIdx.x; e < N_EDGES; e += nFill * 256) {
            int d = __builtin_nontemporal_load(&dst[e]);
            if (d >= lo && d < hi) {
                int s   = __builtin_nontemporal_load(&src[e]);
                int rl  = __builtin_nontemporal_load(&rel[e]);
                float nv = __builtin_nontemporal_load(&norm[e]);
                int tofs = t_offset(s, rl);
                int pos = atomicAdd(&cnt[d], 1);
                if (pos < CAP) {
                    i32x2 p; p.x = tofs; p.y = __float_as_int(nv);
                    payF[(size_t)(d - lo) * CAP + pos] = p;
                } else {
                    int op = atomicAdd(ovfc, 1);
                    if (op < OVF_CAP) {
                        i32x4 o; o.x = d; o.y = tofs;
                        o.z = __float_as_int(nv); o.w = 0;
                        ovf[op] = o;
                    }
                }
            }
        }
    } else {
        // ---- aggregate role ----
        const int b    = blockIdx.x - nFill;
        const int lo   = aggRange * NODES_PER_W;
        const int lane = threadIdx.x & 63;
        const int d    = lo + b * 4 + (threadIdx.x >> 6);

        const int degRaw = __builtin_amdgcn_readfirstlane(cnt[d]);
        const int deg    = min(degRaw, CAP);
        const i32x2* pp  = payG + (size_t)(d - lo) * CAP;

        float acc = 0.f;
        int i = 0;
        for (; i + 4 <= deg; i += 4) {
            i32x2 p0 = __builtin_nontemporal_load(&pp[i]);
            i32x2 p1 = __builtin_nontemporal_load(&pp[i + 1]);
            i32x2 p2 = __builtin_nontemporal_load(&pp[i + 2]);
            i32x2 p3 = __builtin_nontemporal_load(&pp[i + 3]);
            const unsigned short t0 = T[(size_t)(unsigned)p0.x + lane];
            const unsigned short t1 = T[(size_t)(unsigned)p1.x + lane];
            const unsigned short t2 = T[(size_t)(unsigned)p2.x + lane];
            const unsigned short t3 = T[(size_t)(unsigned)p3.x + lane];
            acc = fmaf(__int_as_float(p0.y), bf16_to_f32(t0), acc);
            acc = fmaf(__int_as_float(p1.y), bf16_to_f32(t1), acc);
            acc = fmaf(__int_as_float(p2.y), bf16_to_f32(t2), acc);
            acc = fmaf(__int_as_float(p3.y), bf16_to_f32(t3), acc);
        }
        for (; i < deg; ++i) {
            i32x2 p = __builtin_nontemporal_load(&pp[i]);
            const unsigned short t = T[(size_t)(unsigned)p.x + lane];
            acc = fmaf(__int_as_float(p.y), bf16_to_f32(t), acc);
        }
        if (degRaw > CAP) {                      // exact overflow handling (rare)
            const int no = min(__builtin_amdgcn_readfirstlane(*ovfc), OVF_CAP);
            for (int j = 0; j < no; ++j) {
                i32x4 o = ovf[j];
                if (o.x == d) {
                    const unsigned short t = T[(size_t)(unsigned)o.y + lane];
                    acc = fmaf(__int_as_float(o.z), bf16_to_f32(t), acc);
                }
            }
        }
        out[((size_t)d << 6) + lane] = fmaxf(acc, 0.f);
    }
}

// ---------------- atomic fallback (no workspace) ----------------
__global__ __launch_bounds__(256) void rgcn_edge_kernel(
    const float* __restrict__ h, const float* __restrict__ W,
    const float* __restrict__ norm, const int* __restrict__ src,
    const int* __restrict__ dst, const int* __restrict__ rel,
    float* __restrict__ out)
{
    const int lane = threadIdx.x & 63;
    const int w    = threadIdx.x >> 6;
    const int r    = blockIdx.x & 15;
    const int inst = blockIdx.x >> 4;
    const int wavesPerRel = (gridDim.x >> 4) * 4;
    const int wi   = inst * 4 + w;

    float wreg[64];
    const float* Wr = W + (size_t)r * (FEAT * FEAT) + lane;
    #pragma unroll
    for (int d = 0; d < 64; ++d) wreg[d] = Wr[d * 64];

    const int nChunks = N_EDGES / 64;
    for (int c = wi; c < nChunks; c += wavesPerRel) {
        const int base = c * 64;
        unsigned long long m = __ballot(rel[base + lane] == r);
        while (m) {
            const int idx = __ffsll(m) - 1;
            m &= (m - 1);
            const int e = base + idx;
            const int se = __builtin_amdgcn_readfirstlane(src[e]);
            const int de = __builtin_amdgcn_readfirstlane(dst[e]);
            const float nv = __uint_as_float(
                __builtin_amdgcn_readfirstlane(__float_as_uint(norm[e])));
            const float* hp = h + ((size_t)se << 6);
            f32x16 ha, hb2, hc, hd;
            asm volatile(
                "s_load_dwordx16 %0, %4, 0x0\n\ts_load_dwordx16 %1, %4, 0x40\n\t"
                "s_load_dwordx16 %2, %4, 0x80\n\ts_load_dwordx16 %3, %4, 0xc0\n\t"
                "s_waitcnt lgkmcnt(0)"
                : "=&s"(ha), "=&s"(hb2), "=&s"(hc), "=&s"(hd) : "s"(hp));
            float a0 = 0.f, a1 = 0.f, a2 = 0.f, a3 = 0.f;
            #pragma unroll
            for (int j = 0; j < 16; ++j) {
                a0 = fmaf(ha[j], wreg[j], a0);       a1 = fmaf(hb2[j], wreg[16 + j], a1);
                a2 = fmaf(hc[j], wreg[32 + j], a2);  a3 = fmaf(hd[j], wreg[48 + j], a3);
            }
            unsafeAtomicAdd(&out[(size_t)de * FEAT + lane], ((a0 + a1) + (a2 + a3)) * nv);
        }
    }
}

__global__ __launch_bounds__(256) void relu_kernel(float4* __restrict__ out, int n4)
{
    int i = blockIdx.x * 256 + threadIdx.x;
    if (i < n4) {
        float4 v = out[i];
        v.x = fmaxf(v.x, 0.f); v.y = fmaxf(v.y, 0.f);
        v.z = fmaxf(v.z, 0.f); v.w = fmaxf(v.w, 0.f);
        out[i] = v;
    }
}

// ---------------- host ----------------
static inline size_t align256(size_t x) { return (x + 255) & ~(size_t)255; }

extern "C" void kernel_launch(void* const* d_in, const int* in_sizes, int n_in,
                              void* d_out, int out_size, void* d_ws, size_t ws_size,
                              hipStream_t stream)
{
    (void)in_sizes; (void)n_in;

    const float* h    = (const float*)d_in[0];
    const float* W    = (const float*)d_in[1];
    const float* norm = (const float*)d_in[2];
    const int*   src  = (const int*)d_in[3];
    const int*   dst  = (const int*)d_in[4];
    const int*   rel  = (const int*)d_in[5];
    float*       out  = (float*)d_out;

    const size_t szT    = (size_t)N_NODES * NUM_RELS * FEAT * 2;   // 204.8 MB
    const size_t szHb   = (size_t)N_NODES * FEAT * 2;              // 12.8 MB
    const size_t szWt   = (size_t)NUM_RELS * FEAT * FEAT * 2;      // 128 KB
    const size_t szCnt  = (size_t)N_NODES * 4;                     // 400 KB
    const size_t szPayW = (size_t)NODES_PER_W * CAP * 8;           // 12.8 MB per window
    const size_t szOvf  = (size_t)OVF_CAP * 16;                    // 512 KB

    const size_t needWin = align256(szT) + align256(szHb) + align256(szWt)
                         + 2 * align256(szPayW) + align256(szCnt) + align256(256)
                         + align256(szOvf);                        // ~244.3 MB

    const int n4h = N_NODES * FEAT / 4;

    if (ws_size >= needWin) {
        char* ws = (char*)d_ws; size_t off = 0;
        unsigned short* T    = (unsigned short*)(ws + off); off += align256(szT);
        unsigned short* hb   = (unsigned short*)(ws + off); off += align256(szHb);
        unsigned short* Wt   = (unsigned short*)(ws + off); off += align256(szWt);
        i32x2*          pay0 = (i32x2*)         (ws + off); off += align256(szPayW);
        i32x2*          pay1 = (i32x2*)         (ws + off); off += align256(szPayW);
        int*            cnt  = (int*)           (ws + off); off += align256(szCnt);
        int*            ovfc = (int*)           (ws + off); off += align256(256);
        i32x4*          ovf  = (i32x4*)         (ws + off); off += align256(szOvf);

        hipLaunchKernelGGL(cvt_h_kernel, dim3((n4h + 255) / 256), dim3(256), 0, stream,
                           (const float4*)h, (ushort4*)hb, n4h);
        hipLaunchKernelGGL(cvt_w_kernel, dim3(NUM_RELS * FEAT * FEAT / 256), dim3(256),
                           0, stream, W, Wt);
        hipMemsetAsync(cnt, 0, szCnt, stream);
        hipMemsetAsync(ovfc, 0, 256, stream);

        // K_g: gemm (rel-split, 4x waves) + fill(0) fused
        hipLaunchKernelGGL(gemm_fill_kernel, dim3(NGEMM + FILL_BLOCKS), dim3(256), 0, stream,
                           hb, Wt, T, src, dst, rel, norm, cnt, ovfc, ovf, pay0);

        // K1..K3: fill(r) + agg(r-1); K4: agg(3). Windows alternate 0,1,0,1.
        i32x2* win[2] = {pay0, pay1};
        for (int r = 1; r < RANGES_W; ++r) {
            hipLaunchKernelGGL(fill_agg_kernel, dim3(FILL_BLOCKS + AGG_BLOCKS), dim3(256),
                               0, stream, src, dst, rel, norm, cnt, ovfc, ovf,
                               win[r & 1], win[(r - 1) & 1], T, out, r, r - 1);
        }
        hipLaunchKernelGGL(fill_agg_kernel, dim3(AGG_BLOCKS), dim3(256), 0, stream,
                           src, dst, rel, norm, cnt, ovfc, ovf,
                           (i32x2*)nullptr, win[(RANGES_W - 1) & 1], T, out,
                           -1, RANGES_W - 1);
        return;
    }

    // last-resort atomic path
    hipMemsetAsync(d_out, 0, (size_t)out_size * sizeof(float), stream);
    hipLaunchKernelGGL(rgcn_edge_kernel, dim3(16 * 128), dim3(256), 0, stream,
                       h, W, norm, src, dst, rel, out);
    const int n4 = out_size / 4;
    hipLaunchKernelGGL(relu_kernel, dim3((n4 + 255) / 256), dim3(256), 0, stream,
                       (float4*)d_out, n4);
}